// Round 4
// baseline (468.682 us; speedup 1.0000x reference)
//
#include <hip/hip_runtime.h>
#include <hip/hip_bf16.h>
#include <cstdint>
#include <cstddef>

// Problem constants (match reference setup_inputs)
#define N_NODES 20000
#define N_EDGES 320000
#define DIM_IN  2048
#define DIM_H1  512
#define DIM_H2  128
#define DIM_H3  32
#define NPART   64   // pooled partial buffers
static constexpr float LN_EPS = 1e-5f;

typedef __bf16 bf16x8 __attribute__((ext_vector_type(8)));
typedef __bf16 bf16x4 __attribute__((ext_vector_type(4)));
typedef __bf16 bf16x2 __attribute__((ext_vector_type(2)));
typedef float f32x4 __attribute__((ext_vector_type(4)));

// ---------------------------------------------------------------------------
// Edge dtype detection: reference says int64, but JAX default (x64 disabled)
// downcasts to int32. If int64: viewing as int2, every .y is 0 (values in
// [0,20000)). If int32: .y are random node ids -> P(all 32 zero) ~ 0.
__global__ void detect_fmt_kernel(const void* eraw, int* flag) {
  const int2* p = (const int2*)eraw;
  int all0 = 1;
  for (int i = 0; i < 32; ++i) if (p[i].y != 0) all0 = 0;
  *flag = all0;  // 1 => int64 layout
}

__global__ void convert_edges_kernel(const void* eraw, const int* __restrict__ flag,
                                     int* __restrict__ src, int* __restrict__ dst, int E) {
  const int is64 = *flag;
  for (int e = blockIdx.x * blockDim.x + threadIdx.x; e < E; e += gridDim.x * blockDim.x) {
    if (is64) {
      const long long* p = (const long long*)eraw;
      src[e] = (int)p[e];
      dst[e] = (int)p[(size_t)E + e];
    } else {
      const int* p = (const int*)eraw;
      src[e] = p[e];
      dst[e] = p[(size_t)E + e];
    }
  }
}

__global__ void count_kernel(const int* __restrict__ dst, int* __restrict__ cnt, int E) {
  for (int e = blockIdx.x * blockDim.x + threadIdx.x; e < E; e += gridDim.x * blockDim.x)
    atomicAdd(&cnt[dst[e]], 1);
}

// Exclusive prefix sum of cnt[0..n) -> rowptr[0..n], cursor copy. One block.
__global__ __launch_bounds__(1024) void scan_kernel(const int* __restrict__ cnt,
                                                    int* __restrict__ rowptr,
                                                    int* __restrict__ cursor, int n) {
  __shared__ int s[1024];
  const int t = threadIdx.x;
  const int chunk = (n + 1023) / 1024;
  const int beg = t * chunk;
  const int end = min(beg + chunk, n);
  int sum = 0;
  for (int i = beg; i < end; ++i) sum += cnt[i];
  s[t] = sum;
  __syncthreads();
  for (int d = 1; d < 1024; d <<= 1) {
    int v = (t >= d) ? s[t - d] : 0;
    __syncthreads();
    s[t] += v;
    __syncthreads();
  }
  int run = s[t] - sum;  // exclusive prefix of this thread's chunk
  for (int i = beg; i < end; ++i) { rowptr[i] = run; cursor[i] = run; run += cnt[i]; }
  if (t == 1023) rowptr[n] = s[1023];
}

__global__ void scatter_kernel(const int* __restrict__ src, const int* __restrict__ dst,
                               int* __restrict__ cursor, int* __restrict__ csr_src, int E) {
  for (int e = blockIdx.x * blockDim.x + threadIdx.x; e < E; e += gridDim.x * blockDim.x) {
    int d = dst[e];
    int pos = atomicAdd(&cursor[d], 1);
    csr_src[pos] = src[e];
  }
}

__global__ void dinv_kernel(const int* __restrict__ cnt, float* __restrict__ dinv, int n) {
  int i = blockIdx.x * blockDim.x + threadIdx.x;
  if (i < n) dinv[i] = rsqrtf((float)(cnt[i] + 1));  // +1 self loop; always >= 1
}

// ---------------------------------------------------------------------------
// W[K][N] fp32 -> WT[N][K] bf16 (for MFMA B^T operand). K,N multiples of 32.
__global__ __launch_bounds__(256) void transpose_cvt_kernel(const float* __restrict__ W,
                                                            __bf16* __restrict__ WT,
                                                            int K, int N) {
  __shared__ float t[32][33];
  const int kb = blockIdx.x * 32, nb = blockIdx.y * 32;
  const int tx = threadIdx.x & 31, ty = threadIdx.x >> 5;  // ty: 0..7
  #pragma unroll
  for (int i = 0; i < 32; i += 8)
    t[ty + i][tx] = W[(size_t)(kb + ty + i) * N + nb + tx];
  __syncthreads();
  #pragma unroll
  for (int i = 0; i < 32; i += 8)
    WT[(size_t)(nb + ty + i) * K + kb + tx] = (__bf16)t[tx][ty + i];
}

// ---------------------------------------------------------------------------
// GEMM1 special: C[M][512] bf16 = A[M][K] fp32 @ BT[512][K]^T bf16.
// BM=64, BN=512 (full N -> A fetched exactly once), BK=32, 512 threads.
// 8 waves as 2Mx4N, each computes 32x128 = 2x8 frags of 16x16x32.
// LDS rows padded to 40 bf16 (80 B = 20 banks): fragment ds_read_b128 across
// 16 rows lands 2 rows/bank = free 2-way aliasing (vs 8-way at 64 B stride).
#define LDP 40
__global__ __launch_bounds__(512) void gemm1_kernel(
    const float* __restrict__ A, const __bf16* __restrict__ BT,
    __bf16* __restrict__ C, int M, int K) {
  __shared__ __align__(16) __bf16 Asm[64 * LDP];
  __shared__ __align__(16) __bf16 Bsm[512 * LDP];
  const int tid = threadIdx.x;
  const int wave = tid >> 6;
  const int lane = tid & 63;
  const int row0 = blockIdx.x * 64;
  const int wr = (wave >> 2) * 32;   // 0 or 32
  const int wc = (wave & 3) * 128;   // 0,128,256,384

  f32x4 acc[2][8] = {};

  // A staging coords: thread t covers row t>>3, fp32 cols (t&7)*4
  const int a_r = tid >> 3;
  const int a_c = (tid & 7) * 4;
  int a_gr = row0 + a_r;
  if (a_gr >= M) a_gr = M - 1;  // clamp (rows >= M never stored)
  const float* a_base = A + (size_t)a_gr * K + a_c;
  // B staging: thread t covers BT row t (64 B per K-step)
  const __bf16* b_base = BT + (size_t)tid * K;

  for (int k0 = 0; k0 < K; k0 += 32) {
    float4 va = *(const float4*)(a_base + k0);
    bf16x4 oa;
    oa[0] = (__bf16)va.x; oa[1] = (__bf16)va.y; oa[2] = (__bf16)va.z; oa[3] = (__bf16)va.w;
    *(bf16x4*)&Asm[a_r * LDP + a_c] = oa;
    const bf16x8* bp = (const bf16x8*)(b_base + k0);
    #pragma unroll
    for (int q = 0; q < 4; ++q)
      *(bf16x8*)&Bsm[tid * LDP + q * 8] = bp[q];
    __syncthreads();

    bf16x8 af[2], bfr[8];
    #pragma unroll
    for (int m = 0; m < 2; ++m)
      af[m] = *(const bf16x8*)&Asm[(wr + m * 16 + (lane & 15)) * LDP + (lane >> 4) * 8];
    #pragma unroll
    for (int n = 0; n < 8; ++n)
      bfr[n] = *(const bf16x8*)&Bsm[(wc + n * 16 + (lane & 15)) * LDP + (lane >> 4) * 8];
    #pragma unroll
    for (int m = 0; m < 2; ++m)
      #pragma unroll
      for (int n = 0; n < 8; ++n)
        acc[m][n] = __builtin_amdgcn_mfma_f32_16x16x32_bf16(af[m], bfr[n], acc[m][n], 0, 0, 0);
    __syncthreads();
  }

  // Epilogue: D layout col=lane&15, row=(lane>>4)*4+j
  #pragma unroll
  for (int m = 0; m < 2; ++m) {
    const int r = row0 + wr + m * 16 + (lane >> 4) * 4;
    #pragma unroll
    for (int n = 0; n < 8; ++n) {
      const int c = wc + n * 16 + (lane & 15);
      #pragma unroll
      for (int j = 0; j < 4; ++j)
        if (r + j < M) C[(size_t)(r + j) * 512 + c] = (__bf16)acc[m][n][j];
    }
  }
}

// ---------------------------------------------------------------------------
// bf16 MFMA GEMM (generic 128x128 tile) - used for GEMM2.
template <typename AT, typename CT>
__global__ __launch_bounds__(256) void mfma_gemm_kernel(
    const AT* __restrict__ A, const __bf16* __restrict__ BT,
    CT* __restrict__ C, int M, int N, int K) {
  __shared__ __align__(16) __bf16 Asm[128 * 32];
  __shared__ __align__(16) __bf16 Bsm[128 * 32];
  const int tid = threadIdx.x;
  const int wave = tid >> 6;
  const int lane = tid & 63;
  const int row0 = blockIdx.y * 128;
  const int col0 = blockIdx.x * 128;
  const int wr = (wave >> 1) * 64;
  const int wc = (wave & 1) * 64;

  f32x4 acc[4][4] = {};

  const int s_r = wave * 32 + (lane >> 2);
  const int s_c = (lane & 3) * 8;

  for (int k0 = 0; k0 < K; k0 += 32) {
    #pragma unroll
    for (int i = 0; i < 2; ++i) {
      int r = s_r + i * 16;
      int gr = row0 + r;
      if (gr >= M) gr = M - 1;
      if constexpr (sizeof(AT) == 4) {
        const float* srcp = (const float*)A + (size_t)gr * K + k0 + s_c;
        float4 v0 = *(const float4*)srcp;
        float4 v1 = *(const float4*)(srcp + 4);
        bf16x8 o;
        o[0] = (__bf16)v0.x; o[1] = (__bf16)v0.y; o[2] = (__bf16)v0.z; o[3] = (__bf16)v0.w;
        o[4] = (__bf16)v1.x; o[5] = (__bf16)v1.y; o[6] = (__bf16)v1.z; o[7] = (__bf16)v1.w;
        *(bf16x8*)&Asm[r * 32 + s_c] = o;
      } else {
        const __bf16* srcp = (const __bf16*)A + (size_t)gr * K + k0 + s_c;
        *(bf16x8*)&Asm[r * 32 + s_c] = *(const bf16x8*)srcp;
      }
      const __bf16* bsrc = BT + (size_t)(col0 + r) * K + k0 + s_c;
      *(bf16x8*)&Bsm[r * 32 + s_c] = *(const bf16x8*)bsrc;
    }
    __syncthreads();

    bf16x8 af[4], bfr[4];
    #pragma unroll
    for (int m = 0; m < 4; ++m)
      af[m] = *(const bf16x8*)&Asm[(wr + m * 16 + (lane & 15)) * 32 + (lane >> 4) * 8];
    #pragma unroll
    for (int n = 0; n < 4; ++n)
      bfr[n] = *(const bf16x8*)&Bsm[(wc + n * 16 + (lane & 15)) * 32 + (lane >> 4) * 8];
    #pragma unroll
    for (int m = 0; m < 4; ++m)
      #pragma unroll
      for (int n = 0; n < 4; ++n)
        acc[m][n] = __builtin_amdgcn_mfma_f32_16x16x32_bf16(af[m], bfr[n], acc[m][n], 0, 0, 0);
    __syncthreads();
  }

  #pragma unroll
  for (int m = 0; m < 4; ++m) {
    const int r = row0 + wr + m * 16 + (lane >> 4) * 4;
    #pragma unroll
    for (int n = 0; n < 4; ++n) {
      const int c = col0 + wc + n * 16 + (lane & 15);
      #pragma unroll
      for (int j = 0; j < 4; ++j)
        if (r + j < M) C[(size_t)(r + j) * N + c] = (CT)acc[m][n][j];
    }
  }
}

// ---------------------------------------------------------------------------
// Fused GCN aggregate + bias + LayerNorm + ReLU (fp32 xw input).
template <int F, int TPB, typename OutT>
__global__ __launch_bounds__(TPB) void gcn_agg_ln_relu_kernel(
    const float* __restrict__ xw, const float* __restrict__ dinv,
    const int* __restrict__ rowptr, const int* __restrict__ csr_src,
    const float* __restrict__ bias, const float* __restrict__ gamma,
    const float* __restrict__ beta, OutT* __restrict__ h) {
  constexpr int NF = (F + TPB - 1) / TPB;
  const int i = blockIdx.x;
  const int tid = threadIdx.x;
  const float di = dinv[i];
  float acc[NF];
  #pragma unroll
  for (int q = 0; q < NF; ++q) {
    int f = tid + q * TPB;
    acc[q] = (f < F) ? di * xw[(size_t)i * F + f] : 0.f;  // self loop
  }
  const int beg = rowptr[i], end = rowptr[i + 1];
  for (int j = beg; j < end; ++j) {
    int s = csr_src[j];
    float c = dinv[s];
    const float* row = xw + (size_t)s * F;
    #pragma unroll
    for (int q = 0; q < NF; ++q) {
      int f = tid + q * TPB;
      if (f < F) acc[q] += c * row[f];
    }
  }
  float sum = 0.f, sumsq = 0.f;
  #pragma unroll
  for (int q = 0; q < NF; ++q) {
    int f = tid + q * TPB;
    if (f < F) {
      float v = di * acc[q] + bias[f];
      acc[q] = v;
      sum += v;
      sumsq += v * v;
    }
  }
  #pragma unroll
  for (int m = 32; m >= 1; m >>= 1) {
    sum += __shfl_xor(sum, m);
    sumsq += __shfl_xor(sumsq, m);
  }
  constexpr int NW = TPB / 64;
  __shared__ float red[2][NW];
  const int wid = tid >> 6, lane = tid & 63;
  if (lane == 0) { red[0][wid] = sum; red[1][wid] = sumsq; }
  __syncthreads();
  if (tid == 0) {
    float a = 0.f, b2 = 0.f;
    for (int w = 0; w < NW; ++w) { a += red[0][w]; b2 += red[1][w]; }
    red[0][0] = a;
    red[1][0] = b2;
  }
  __syncthreads();
  const float mu = red[0][0] / F;
  const float var = red[1][0] / F - mu * mu;
  const float rstd = rsqrtf(var + LN_EPS);
  #pragma unroll
  for (int q = 0; q < NF; ++q) {
    int f = tid + q * TPB;
    if (f < F) h[(size_t)i * F + f] = (OutT)fmaxf(0.f, (acc[q] - mu) * rstd * gamma[f] + beta[f]);
  }
}

// bf16-input variant: each thread owns 2 consecutive features (one 4B load
// per neighbor row -> coalesced). F == 2*TPB. fp32 accumulate, bf16 out.
template <int F, int TPB>
__global__ __launch_bounds__(TPB) void gcn_agg_ln_relu_bf16_kernel(
    const __bf16* __restrict__ xw, const float* __restrict__ dinv,
    const int* __restrict__ rowptr, const int* __restrict__ csr_src,
    const float* __restrict__ bias, const float* __restrict__ gamma,
    const float* __restrict__ beta, __bf16* __restrict__ h) {
  static_assert(F == 2 * TPB, "layout");
  const int i = blockIdx.x;
  const int tid = threadIdx.x;
  const int f0 = tid * 2;
  const float di = dinv[i];
  bf16x2 v = *(const bf16x2*)&xw[(size_t)i * F + f0];
  float a0 = di * (float)v[0];
  float a1 = di * (float)v[1];
  const int beg = rowptr[i], end = rowptr[i + 1];
  for (int j = beg; j < end; ++j) {
    int s = csr_src[j];
    float c = dinv[s];
    bf16x2 r = *(const bf16x2*)&xw[(size_t)s * F + f0];
    a0 += c * (float)r[0];
    a1 += c * (float)r[1];
  }
  a0 = di * a0 + bias[f0];
  a1 = di * a1 + bias[f0 + 1];
  float sum = a0 + a1;
  float sumsq = a0 * a0 + a1 * a1;
  #pragma unroll
  for (int m = 32; m >= 1; m >>= 1) {
    sum += __shfl_xor(sum, m);
    sumsq += __shfl_xor(sumsq, m);
  }
  constexpr int NW = TPB / 64;
  __shared__ float red[2][NW];
  const int wid = tid >> 6, lane = tid & 63;
  if (lane == 0) { red[0][wid] = sum; red[1][wid] = sumsq; }
  __syncthreads();
  if (tid == 0) {
    float a = 0.f, b2 = 0.f;
    for (int w = 0; w < NW; ++w) { a += red[0][w]; b2 += red[1][w]; }
    red[0][0] = a;
    red[1][0] = b2;
  }
  __syncthreads();
  const float mu = red[0][0] / F;
  const float var = red[1][0] / F - mu * mu;
  const float rstd = rsqrtf(var + LN_EPS);
  bf16x2 o;
  o[0] = (__bf16)fmaxf(0.f, (a0 - mu) * rstd * gamma[f0] + beta[f0]);
  o[1] = (__bf16)fmaxf(0.f, (a1 - mu) * rstd * gamma[f0 + 1] + beta[f0 + 1]);
  *(bf16x2*)&h[(size_t)i * F + f0] = o;
}

// ---------------------------------------------------------------------------
// fp32 tiled GEMM (kept for the tiny GEMM3 / GAT-GEMM). 256 threads.
template <int BM, int BN, int BK, int TM, int TN>
__global__ __launch_bounds__((BM / TM) * (BN / TN)) void sgemm_kernel(
    const float* __restrict__ A, const float* __restrict__ B, float* __restrict__ C,
    int M, int N, int K) {
  constexpr int THREADS = (BM / TM) * (BN / TN);
  __shared__ float As[BK][BM + 4];
  __shared__ float Bs[BK][BN];
  const int tid = threadIdx.x;
  const int tcol = tid % (BN / TN);
  const int trow = tid / (BN / TN);
  const int row0 = blockIdx.y * BM;
  const int col0 = blockIdx.x * BN;
  float acc[TM][TN] = {};
  for (int k0 = 0; k0 < K; k0 += BK) {
    constexpr int A4 = BM * BK / 4;
    #pragma unroll
    for (int i = tid; i < A4; i += THREADS) {
      int r = i / (BK / 4);
      int c4 = i % (BK / 4);
      int gr = row0 + r;
      float4 v = make_float4(0.f, 0.f, 0.f, 0.f);
      if (gr < M) v = *(const float4*)(A + (size_t)gr * K + k0 + c4 * 4);
      As[c4 * 4 + 0][r] = v.x;
      As[c4 * 4 + 1][r] = v.y;
      As[c4 * 4 + 2][r] = v.z;
      As[c4 * 4 + 3][r] = v.w;
    }
    constexpr int B4 = BK * BN / 4;
    #pragma unroll
    for (int i = tid; i < B4; i += THREADS) {
      int r = i / (BN / 4);
      int c4 = i % (BN / 4);
      float4 v = *(const float4*)(B + (size_t)(k0 + r) * N + col0 + c4 * 4);
      *(float4*)(&Bs[r][c4 * 4]) = v;
    }
    __syncthreads();
    #pragma unroll
    for (int kk = 0; kk < BK; ++kk) {
      float ra[TM], rb[TN];
      #pragma unroll
      for (int i = 0; i < TM; ++i) ra[i] = As[kk][trow * TM + i];
      #pragma unroll
      for (int j = 0; j < TN; ++j) rb[j] = Bs[kk][tcol * TN + j];
      #pragma unroll
      for (int i = 0; i < TM; ++i)
        #pragma unroll
        for (int j = 0; j < TN; ++j) acc[i][j] = fmaf(ra[i], rb[j], acc[i][j]);
    }
    __syncthreads();
  }
  #pragma unroll
  for (int i = 0; i < TM; ++i) {
    int gr = row0 + trow * TM + i;
    if (gr >= M) continue;
    #pragma unroll
    for (int j = 0; j < TN; ++j) {
      int gc = col0 + tcol * TN + j;
      if (gc < N) C[(size_t)gr * N + gc] = acc[i][j];
    }
  }
}

// ---------------------------------------------------------------------------
// GAT: per-node attention scores s_src, s_dst (dot with att vectors)
__global__ void gat_sdots_kernel(const float* __restrict__ xwg,
                                 const float* __restrict__ att_src,
                                 const float* __restrict__ att_dst,
                                 float* __restrict__ s_src, float* __restrict__ s_dst, int n) {
  int gid = blockIdx.x * blockDim.x + threadIdx.x;
  int node = gid >> 5;
  int l = threadIdx.x & 31;
  if (node >= n) return;
  float v = xwg[(size_t)node * 32 + l];
  float vs = v * att_src[l];
  float vd = v * att_dst[l];
  #pragma unroll
  for (int m = 16; m >= 1; m >>= 1) {
    vs += __shfl_xor(vs, m);
    vd += __shfl_xor(vd, m);
  }
  if (l == 0) { s_src[node] = vs; s_dst[node] = vd; }
}

__device__ __forceinline__ float leaky02(float x) { return x > 0.f ? x : 0.2f * x; }

// GAT online-softmax aggregate + bias + ReLU + pooled partial accumulation.
// 64 threads = 2 softmax groups (lane>>5), alternate edges, shfl-combine.
__global__ __launch_bounds__(64) void gat_agg_kernel(
    const float* __restrict__ xwg, const float* __restrict__ s_src,
    const float* __restrict__ s_dst, const int* __restrict__ rowptr,
    const int* __restrict__ csr_src, const float* __restrict__ bg,
    float* __restrict__ pooled_part) {
  const int i = blockIdx.x;
  const int lane = threadIdx.x;
  const int f = lane & 31;
  const int half = lane >> 5;
  const float sd = s_dst[i];
  // group 0 takes the self loop; group 1 starts empty
  float m, den, acc;
  if (half == 0) {
    m = leaky02(s_src[i] + sd);
    den = 1.f;
    acc = xwg[(size_t)i * 32 + f];
  } else {
    m = -3.0e38f;
    den = 0.f;
    acc = 0.f;
  }
  const int beg = rowptr[i], end = rowptr[i + 1];
  for (int j = beg + half; j < end; j += 2) {
    int s = csr_src[j];
    float a = leaky02(s_src[s] + sd);
    float mn = fmaxf(m, a);
    float sc = __expf(m - mn);
    float ea = __expf(a - mn);
    acc = acc * sc + ea * xwg[(size_t)s * 32 + f];
    den = den * sc + ea;
    m = mn;
  }
  // combine the two groups
  float m_o = __shfl_xor(m, 32);
  float den_o = __shfl_xor(den, 32);
  float acc_o = __shfl_xor(acc, 32);
  float mn = fmaxf(m, m_o);
  float sc = __expf(m - mn);
  float so = __expf(m_o - mn);
  float den_t = den * sc + den_o * so;
  float acc_t = acc * sc + acc_o * so;
  float out = fmaxf(acc_t / den_t + bg[f], 0.f);
  if (lane < 32) atomicAdd(&pooled_part[(size_t)(i & (NPART - 1)) * 32 + f], out);
}

__global__ __launch_bounds__(64) void final_fc_kernel(const float* __restrict__ pooled_part,
                                                      const float* __restrict__ fc_w,
                                                      const float* __restrict__ fc_b,
                                                      float* __restrict__ out, float invN) {
  const int lane = threadIdx.x;
  const int f = lane & 31, half = lane >> 5;
  float p = 0.f;
  #pragma unroll
  for (int b = 0; b < NPART / 2; ++b)
    p += pooled_part[(size_t)(half * (NPART / 2) + b) * 32 + f];
  p += __shfl_xor(p, 32);
  p *= invN;
  #pragma unroll
  for (int c = 0; c < 2; ++c) {
    float v = (lane < 32) ? p * fc_w[f * 2 + c] : 0.f;
    #pragma unroll
    for (int m = 16; m >= 1; m >>= 1) v += __shfl_xor(v, m);
    if (lane == 0) out[c] = v + fc_b[c];
  }
}

// ---------------------------------------------------------------------------
extern "C" void kernel_launch(void* const* d_in, const int* in_sizes, int n_in,
                              void* d_out, int out_size, void* d_ws, size_t ws_size,
                              hipStream_t stream) {
  const float* x       = (const float*)d_in[0];
  const void*  edges   = d_in[1];
  const float* W1      = (const float*)d_in[2];
  const float* b1      = (const float*)d_in[3];
  const float* ln1_g   = (const float*)d_in[4];
  const float* ln1_b   = (const float*)d_in[5];
  const float* W2      = (const float*)d_in[6];
  const float* b2      = (const float*)d_in[7];
  const float* ln2_g   = (const float*)d_in[8];
  const float* ln2_b   = (const float*)d_in[9];
  const float* W3      = (const float*)d_in[10];
  const float* b3      = (const float*)d_in[11];
  const float* ln3_g   = (const float*)d_in[12];
  const float* ln3_b   = (const float*)d_in[13];
  const float* Wg      = (const float*)d_in[14];
  const float* att_src = (const float*)d_in[15];
  const float* att_dst = (const float*)d_in[16];
  const float* bg      = (const float*)d_in[17];
  const float* fc_w    = (const float*)d_in[18];
  const float* fc_b    = (const float*)d_in[19];
  float* out = (float*)d_out;

  const int N = N_NODES, E = N_EDGES;

  // workspace layout
  char* ws = (char*)d_ws;
  size_t off = 0;
  auto alloc = [&](size_t bytes) {
    size_t o = off;
    off = (off + bytes + 255) & ~(size_t)255;
    return o;
  };
  size_t o_bufA   = alloc((size_t)N * DIM_H1 * 4);
  size_t o_bufB   = alloc((size_t)N * DIM_H1 * 4);
  size_t o_w1t    = alloc((size_t)DIM_IN * DIM_H1 * 2);
  size_t o_w2t    = alloc((size_t)DIM_H1 * DIM_H2 * 2);
  size_t o_src    = alloc((size_t)E * 4);
  size_t o_dst    = alloc((size_t)E * 4);
  size_t o_csr    = alloc((size_t)E * 4);
  size_t o_cnt    = alloc((size_t)N * 4);
  size_t o_rowptr = alloc((size_t)(N + 1) * 4);
  size_t o_cursor = alloc((size_t)N * 4);
  size_t o_dinv   = alloc((size_t)N * 4);
  size_t o_ssrc   = alloc((size_t)N * 4);
  size_t o_sdst   = alloc((size_t)N * 4);
  size_t o_pooled = alloc((size_t)NPART * 32 * 4);
  size_t o_flag   = alloc(4);

  float* bufA   = (float*)(ws + o_bufA);
  float* bufB   = (float*)(ws + o_bufB);
  __bf16* W1T   = (__bf16*)(ws + o_w1t);
  __bf16* W2T   = (__bf16*)(ws + o_w2t);
  int*   srcI   = (int*)(ws + o_src);
  int*   dstI   = (int*)(ws + o_dst);
  int*   csr    = (int*)(ws + o_csr);
  int*   cnt    = (int*)(ws + o_cnt);
  int*   rowptr = (int*)(ws + o_rowptr);
  int*   cursor = (int*)(ws + o_cursor);
  float* dinv   = (float*)(ws + o_dinv);
  float* ssrc   = (float*)(ws + o_ssrc);
  float* sdst   = (float*)(ws + o_sdst);
  float* pooled = (float*)(ws + o_pooled);
  int*   flag   = (int*)(ws + o_flag);

  hipMemsetAsync(cnt, 0, (size_t)N * 4, stream);
  hipMemsetAsync(pooled, 0, (size_t)NPART * 32 * 4, stream);

  const int EB = (E + 255) / 256;

  // Graph preprocessing (CSR by dst, reused by all 4 conv layers)
  detect_fmt_kernel<<<1, 1, 0, stream>>>(edges, flag);
  convert_edges_kernel<<<EB, 256, 0, stream>>>(edges, flag, srcI, dstI, E);
  count_kernel<<<EB, 256, 0, stream>>>(dstI, cnt, E);
  scan_kernel<<<1, 1024, 0, stream>>>(cnt, rowptr, cursor, N);
  scatter_kernel<<<EB, 256, 0, stream>>>(srcI, dstI, cursor, csr, E);
  dinv_kernel<<<(N + 255) / 256, 256, 0, stream>>>(cnt, dinv, N);

  // Weight transposes (bf16 B^T operands for the MFMA GEMMs)
  transpose_cvt_kernel<<<dim3(DIM_IN / 32, DIM_H1 / 32), 256, 0, stream>>>(W1, W1T, DIM_IN, DIM_H1);
  transpose_cvt_kernel<<<dim3(DIM_H1 / 32, DIM_H2 / 32), 256, 0, stream>>>(W2, W2T, DIM_H1, DIM_H2);

  const int MB128 = (N + 127) / 128;  // 157
  const int MB64  = (N + 63) / 64;    // 313

  // Layer 1: xw1 = x @ W1 (BN=512 one-pass MFMA; A fetched once; bf16 out)
  gemm1_kernel<<<MB64, 512, 0, stream>>>(x, W1T, (__bf16*)bufA, N, DIM_IN);
  gcn_agg_ln_relu_bf16_kernel<DIM_H1, 256>
      <<<N, 256, 0, stream>>>((const __bf16*)bufA, dinv, rowptr, csr, b1, ln1_g, ln1_b, (__bf16*)bufB);

  // Layer 2: xw2 = h1(bf16) @ W2 (bf16 MFMA, fp32 out)
  mfma_gemm_kernel<__bf16, float>
      <<<dim3(DIM_H2 / 128, MB128), 256, 0, stream>>>((const __bf16*)bufB, W2T, bufA, N, DIM_H2, DIM_H1);
  gcn_agg_ln_relu_kernel<DIM_H2, 128, float>
      <<<N, 128, 0, stream>>>(bufA, dinv, rowptr, csr, b2, ln2_g, ln2_b, bufB);

  // Layer 3: xw3 = h2 @ W3 (20000x128x32, tiny -> fp32 sgemm)
  sgemm_kernel<128, 32, 16, 8, 2>
      <<<dim3(1, MB128), 256, 0, stream>>>(bufB, W3, bufA, N, DIM_H3, DIM_H2);
  gcn_agg_ln_relu_kernel<DIM_H3, 64, float>
      <<<N, 64, 0, stream>>>(bufA, dinv, rowptr, csr, b3, ln3_g, ln3_b, bufB);

  // GAT: xwg = h3 @ Wg (20000x32x32)
  sgemm_kernel<128, 32, 16, 8, 2>
      <<<dim3(1, MB128), 256, 0, stream>>>(bufB, Wg, bufA, N, DIM_H3, DIM_H3);
  gat_sdots_kernel<<<(N * 32 + 255) / 256, 256, 0, stream>>>(bufA, att_src, att_dst, ssrc, sdst, N);
  gat_agg_kernel<<<N, 64, 0, stream>>>(bufA, ssrc, sdst, rowptr, csr, bg, pooled);

  final_fc_kernel<<<1, 64, 0, stream>>>(pooled, fc_w, fc_b, out, 1.f / (float)N);
}

// Round 5
// 416.697 us; speedup vs baseline: 1.1248x; 1.1248x over previous
//
#include <hip/hip_runtime.h>
#include <hip/hip_bf16.h>
#include <cstdint>
#include <cstddef>

// Problem constants (match reference setup_inputs)
#define N_NODES 20000
#define N_EDGES 320000
#define DIM_IN  2048
#define DIM_H1  512
#define DIM_H2  128
#define DIM_H3  32
#define NPART   64   // pooled partial buffers
static constexpr float LN_EPS = 1e-5f;

typedef __bf16 bf16x8 __attribute__((ext_vector_type(8)));
typedef __bf16 bf16x2 __attribute__((ext_vector_type(2)));
typedef float f32x4 __attribute__((ext_vector_type(4)));

// ---------------------------------------------------------------------------
// Edge dtype detection: reference says int64, but JAX default (x64 disabled)
// downcasts to int32. If int64: viewing as int2, every .y is 0 (values in
// [0,20000)). If int32: .y are random node ids -> P(all 32 zero) ~ 0.
__global__ void detect_fmt_kernel(const void* eraw, int* flag) {
  const int2* p = (const int2*)eraw;
  int all0 = 1;
  for (int i = 0; i < 32; ++i) if (p[i].y != 0) all0 = 0;
  *flag = all0;  // 1 => int64 layout
}

__global__ void convert_edges_kernel(const void* eraw, const int* __restrict__ flag,
                                     int* __restrict__ src, int* __restrict__ dst, int E) {
  const int is64 = *flag;
  for (int e = blockIdx.x * blockDim.x + threadIdx.x; e < E; e += gridDim.x * blockDim.x) {
    if (is64) {
      const long long* p = (const long long*)eraw;
      src[e] = (int)p[e];
      dst[e] = (int)p[(size_t)E + e];
    } else {
      const int* p = (const int*)eraw;
      src[e] = p[e];
      dst[e] = p[(size_t)E + e];
    }
  }
}

__global__ void count_kernel(const int* __restrict__ dst, int* __restrict__ cnt, int E) {
  for (int e = blockIdx.x * blockDim.x + threadIdx.x; e < E; e += gridDim.x * blockDim.x)
    atomicAdd(&cnt[dst[e]], 1);
}

// Exclusive prefix sum of cnt[0..n) -> rowptr[0..n], cursor copy. One block.
__global__ __launch_bounds__(1024) void scan_kernel(const int* __restrict__ cnt,
                                                    int* __restrict__ rowptr,
                                                    int* __restrict__ cursor, int n) {
  __shared__ int s[1024];
  const int t = threadIdx.x;
  const int chunk = (n + 1023) / 1024;
  const int beg = t * chunk;
  const int end = min(beg + chunk, n);
  int sum = 0;
  for (int i = beg; i < end; ++i) sum += cnt[i];
  s[t] = sum;
  __syncthreads();
  for (int d = 1; d < 1024; d <<= 1) {
    int v = (t >= d) ? s[t - d] : 0;
    __syncthreads();
    s[t] += v;
    __syncthreads();
  }
  int run = s[t] - sum;  // exclusive prefix of this thread's chunk
  for (int i = beg; i < end; ++i) { rowptr[i] = run; cursor[i] = run; run += cnt[i]; }
  if (t == 1023) rowptr[n] = s[1023];
}

__global__ void scatter_kernel(const int* __restrict__ src, const int* __restrict__ dst,
                               int* __restrict__ cursor, int* __restrict__ csr_src, int E) {
  for (int e = blockIdx.x * blockDim.x + threadIdx.x; e < E; e += gridDim.x * blockDim.x) {
    int d = dst[e];
    int pos = atomicAdd(&cursor[d], 1);
    csr_src[pos] = src[e];
  }
}

__global__ void dinv_kernel(const int* __restrict__ cnt, float* __restrict__ dinv, int n) {
  int i = blockIdx.x * blockDim.x + threadIdx.x;
  if (i < n) dinv[i] = rsqrtf((float)(cnt[i] + 1));  // +1 self loop; always >= 1
}

// ---------------------------------------------------------------------------
// W[K][N] fp32 -> WT[N][K] bf16 (for MFMA B^T operand). K,N multiples of 32.
__global__ __launch_bounds__(256) void transpose_cvt_kernel(const float* __restrict__ W,
                                                            __bf16* __restrict__ WT,
                                                            int K, int N) {
  __shared__ float t[32][33];
  const int kb = blockIdx.x * 32, nb = blockIdx.y * 32;
  const int tx = threadIdx.x & 31, ty = threadIdx.x >> 5;  // ty: 0..7
  #pragma unroll
  for (int i = 0; i < 32; i += 8)
    t[ty + i][tx] = W[(size_t)(kb + ty + i) * N + nb + tx];
  __syncthreads();
  #pragma unroll
  for (int i = 0; i < 32; i += 8)
    WT[(size_t)(nb + ty + i) * K + kb + tx] = (__bf16)t[tx][ty + i];
}

// ---------------------------------------------------------------------------
// bf16 MFMA GEMM, 64x128 tile, BK=32, 256 threads (4 waves, 2Mx2N of 32x64).
// Small tile -> ~5 blocks/CU resident: cross-block wave overlap hides the
// 2-barrier K-step drain (R4 lesson: 1.2 blocks/CU = everything stalls).
// LDS rows padded to 34 bf16 (68 B = 17 banks, odd): fragment ds_read_b128
// across 16 rows spreads all 32 banks (R3/R4 had 8-way conflicts).
// AT=float: fp32->bf16 convert in staging. CT=float|__bf16 out.
// Grid: (Mtiles, N/128) - M-major so one col-pass streams A through L3 once.
#define LDP 34
template <typename AT, typename CT>
__global__ __launch_bounds__(256, 4) void gemm64_kernel(
    const AT* __restrict__ A, const __bf16* __restrict__ BT,
    CT* __restrict__ C, int M, int N, int K) {
  __shared__ __align__(16) __bf16 Asm[64 * LDP];
  __shared__ __align__(16) __bf16 Bsm[128 * LDP];
  const int tid = threadIdx.x;
  const int wave = tid >> 6;
  const int lane = tid & 63;
  const int row0 = blockIdx.x * 64;
  const int col0 = blockIdx.y * 128;
  const int wr = (wave >> 1) * 32;  // 0/32
  const int wc = (wave & 1) * 64;   // 0/64

  f32x4 acc[2][4] = {};

  // A staging: thread -> row tid>>2 (0..63), cols (tid&3)*8 .. +8
  const int a_r = tid >> 2, a_c = (tid & 3) * 8;
  int a_gr = row0 + a_r;
  if (a_gr >= M) a_gr = M - 1;  // clamp; rows >= M never stored
  const AT* a_base = A + (size_t)a_gr * K + a_c;
  // B staging: thread -> BT row tid>>1 (0..127), cols (tid&1)*16 .. +16
  const int b_r = tid >> 1, b_c = (tid & 1) * 16;
  const __bf16* b_base = BT + (size_t)(col0 + b_r) * K + b_c;

  for (int k0 = 0; k0 < K; k0 += 32) {
    if constexpr (sizeof(AT) == 4) {
      float4 v0 = *(const float4*)((const float*)a_base + k0);
      float4 v1 = *(const float4*)((const float*)a_base + k0 + 4);
      bf16x8 o;
      o[0] = (__bf16)v0.x; o[1] = (__bf16)v0.y; o[2] = (__bf16)v0.z; o[3] = (__bf16)v0.w;
      o[4] = (__bf16)v1.x; o[5] = (__bf16)v1.y; o[6] = (__bf16)v1.z; o[7] = (__bf16)v1.w;
      *(bf16x8*)&Asm[a_r * LDP + a_c] = o;
    } else {
      *(bf16x8*)&Asm[a_r * LDP + a_c] = *(const bf16x8*)((const __bf16*)a_base + k0);
    }
    *(bf16x8*)&Bsm[b_r * LDP + b_c] = *(const bf16x8*)(b_base + k0);
    *(bf16x8*)&Bsm[b_r * LDP + b_c + 8] = *(const bf16x8*)(b_base + k0 + 8);
    __syncthreads();

    bf16x8 af[2], bfr[4];
    #pragma unroll
    for (int m = 0; m < 2; ++m)
      af[m] = *(const bf16x8*)&Asm[(wr + m * 16 + (lane & 15)) * LDP + (lane >> 4) * 8];
    #pragma unroll
    for (int n = 0; n < 4; ++n)
      bfr[n] = *(const bf16x8*)&Bsm[(wc + n * 16 + (lane & 15)) * LDP + (lane >> 4) * 8];
    #pragma unroll
    for (int m = 0; m < 2; ++m)
      #pragma unroll
      for (int n = 0; n < 4; ++n)
        acc[m][n] = __builtin_amdgcn_mfma_f32_16x16x32_bf16(af[m], bfr[n], acc[m][n], 0, 0, 0);
    __syncthreads();
  }

  // Epilogue: D layout col=lane&15, row=(lane>>4)*4+j (m89-verified)
  #pragma unroll
  for (int m = 0; m < 2; ++m) {
    const int r = row0 + wr + m * 16 + (lane >> 4) * 4;
    #pragma unroll
    for (int n = 0; n < 4; ++n) {
      const int c = col0 + wc + n * 16 + (lane & 15);
      #pragma unroll
      for (int j = 0; j < 4; ++j)
        if (r + j < M) C[(size_t)(r + j) * N + c] = (CT)acc[m][n][j];
    }
  }
}

// ---------------------------------------------------------------------------
// Fused GCN aggregate + bias + LayerNorm + ReLU (fp32 xw input).
template <int F, int TPB, typename OutT>
__global__ __launch_bounds__(TPB) void gcn_agg_ln_relu_kernel(
    const float* __restrict__ xw, const float* __restrict__ dinv,
    const int* __restrict__ rowptr, const int* __restrict__ csr_src,
    const float* __restrict__ bias, const float* __restrict__ gamma,
    const float* __restrict__ beta, OutT* __restrict__ h) {
  constexpr int NF = (F + TPB - 1) / TPB;
  const int i = blockIdx.x;
  const int tid = threadIdx.x;
  const float di = dinv[i];
  float acc[NF];
  #pragma unroll
  for (int q = 0; q < NF; ++q) {
    int f = tid + q * TPB;
    acc[q] = (f < F) ? di * xw[(size_t)i * F + f] : 0.f;  // self loop
  }
  const int beg = rowptr[i], end = rowptr[i + 1];
  for (int j = beg; j < end; ++j) {
    int s = csr_src[j];
    float c = dinv[s];
    const float* row = xw + (size_t)s * F;
    #pragma unroll
    for (int q = 0; q < NF; ++q) {
      int f = tid + q * TPB;
      if (f < F) acc[q] += c * row[f];
    }
  }
  float sum = 0.f, sumsq = 0.f;
  #pragma unroll
  for (int q = 0; q < NF; ++q) {
    int f = tid + q * TPB;
    if (f < F) {
      float v = di * acc[q] + bias[f];
      acc[q] = v;
      sum += v;
      sumsq += v * v;
    }
  }
  #pragma unroll
  for (int m = 32; m >= 1; m >>= 1) {
    sum += __shfl_xor(sum, m);
    sumsq += __shfl_xor(sumsq, m);
  }
  constexpr int NW = TPB / 64;
  __shared__ float red[2][NW];
  const int wid = tid >> 6, lane = tid & 63;
  if (lane == 0) { red[0][wid] = sum; red[1][wid] = sumsq; }
  __syncthreads();
  if (tid == 0) {
    float a = 0.f, b2 = 0.f;
    for (int w = 0; w < NW; ++w) { a += red[0][w]; b2 += red[1][w]; }
    red[0][0] = a;
    red[1][0] = b2;
  }
  __syncthreads();
  const float mu = red[0][0] / F;
  const float var = red[1][0] / F - mu * mu;
  const float rstd = rsqrtf(var + LN_EPS);
  #pragma unroll
  for (int q = 0; q < NF; ++q) {
    int f = tid + q * TPB;
    if (f < F) h[(size_t)i * F + f] = (OutT)fmaxf(0.f, (acc[q] - mu) * rstd * gamma[f] + beta[f]);
  }
}

// bf16-input variant: each thread owns 2 consecutive features (one 4B load
// per neighbor row -> coalesced). F == 2*TPB. fp32 accumulate, bf16 out.
template <int F, int TPB>
__global__ __launch_bounds__(TPB) void gcn_agg_ln_relu_bf16_kernel(
    const __bf16* __restrict__ xw, const float* __restrict__ dinv,
    const int* __restrict__ rowptr, const int* __restrict__ csr_src,
    const float* __restrict__ bias, const float* __restrict__ gamma,
    const float* __restrict__ beta, __bf16* __restrict__ h) {
  static_assert(F == 2 * TPB, "layout");
  const int i = blockIdx.x;
  const int tid = threadIdx.x;
  const int f0 = tid * 2;
  const float di = dinv[i];
  bf16x2 v = *(const bf16x2*)&xw[(size_t)i * F + f0];
  float a0 = di * (float)v[0];
  float a1 = di * (float)v[1];
  const int beg = rowptr[i], end = rowptr[i + 1];
  for (int j = beg; j < end; ++j) {
    int s = csr_src[j];
    float c = dinv[s];
    bf16x2 r = *(const bf16x2*)&xw[(size_t)s * F + f0];
    a0 += c * (float)r[0];
    a1 += c * (float)r[1];
  }
  a0 = di * a0 + bias[f0];
  a1 = di * a1 + bias[f0 + 1];
  float sum = a0 + a1;
  float sumsq = a0 * a0 + a1 * a1;
  #pragma unroll
  for (int m = 32; m >= 1; m >>= 1) {
    sum += __shfl_xor(sum, m);
    sumsq += __shfl_xor(sumsq, m);
  }
  constexpr int NW = TPB / 64;
  __shared__ float red[2][NW];
  const int wid = tid >> 6, lane = tid & 63;
  if (lane == 0) { red[0][wid] = sum; red[1][wid] = sumsq; }
  __syncthreads();
  if (tid == 0) {
    float a = 0.f, b2 = 0.f;
    for (int w = 0; w < NW; ++w) { a += red[0][w]; b2 += red[1][w]; }
    red[0][0] = a;
    red[1][0] = b2;
  }
  __syncthreads();
  const float mu = red[0][0] / F;
  const float var = red[1][0] / F - mu * mu;
  const float rstd = rsqrtf(var + LN_EPS);
  bf16x2 o;
  o[0] = (__bf16)fmaxf(0.f, (a0 - mu) * rstd * gamma[f0] + beta[f0]);
  o[1] = (__bf16)fmaxf(0.f, (a1 - mu) * rstd * gamma[f0 + 1] + beta[f0 + 1]);
  *(bf16x2*)&h[(size_t)i * F + f0] = o;
}

// ---------------------------------------------------------------------------
// fp32 tiled GEMM (kept for the tiny GEMM3 / GAT-GEMM). 256 threads.
template <int BM, int BN, int BK, int TM, int TN>
__global__ __launch_bounds__((BM / TM) * (BN / TN)) void sgemm_kernel(
    const float* __restrict__ A, const float* __restrict__ B, float* __restrict__ C,
    int M, int N, int K) {
  constexpr int THREADS = (BM / TM) * (BN / TN);
  __shared__ float As[BK][BM + 4];
  __shared__ float Bs[BK][BN];
  const int tid = threadIdx.x;
  const int tcol = tid % (BN / TN);
  const int trow = tid / (BN / TN);
  const int row0 = blockIdx.y * BM;
  const int col0 = blockIdx.x * BN;
  float acc[TM][TN] = {};
  for (int k0 = 0; k0 < K; k0 += BK) {
    constexpr int A4 = BM * BK / 4;
    #pragma unroll
    for (int i = tid; i < A4; i += THREADS) {
      int r = i / (BK / 4);
      int c4 = i % (BK / 4);
      int gr = row0 + r;
      float4 v = make_float4(0.f, 0.f, 0.f, 0.f);
      if (gr < M) v = *(const float4*)(A + (size_t)gr * K + k0 + c4 * 4);
      As[c4 * 4 + 0][r] = v.x;
      As[c4 * 4 + 1][r] = v.y;
      As[c4 * 4 + 2][r] = v.z;
      As[c4 * 4 + 3][r] = v.w;
    }
    constexpr int B4 = BK * BN / 4;
    #pragma unroll
    for (int i = tid; i < B4; i += THREADS) {
      int r = i / (BN / 4);
      int c4 = i % (BN / 4);
      float4 v = *(const float4*)(B + (size_t)(k0 + r) * N + col0 + c4 * 4);
      *(float4*)(&Bs[r][c4 * 4]) = v;
    }
    __syncthreads();
    #pragma unroll
    for (int kk = 0; kk < BK; ++kk) {
      float ra[TM], rb[TN];
      #pragma unroll
      for (int i = 0; i < TM; ++i) ra[i] = As[kk][trow * TM + i];
      #pragma unroll
      for (int j = 0; j < TN; ++j) rb[j] = Bs[kk][tcol * TN + j];
      #pragma unroll
      for (int i = 0; i < TM; ++i)
        #pragma unroll
        for (int j = 0; j < TN; ++j) acc[i][j] = fmaf(ra[i], rb[j], acc[i][j]);
    }
    __syncthreads();
  }
  #pragma unroll
  for (int i = 0; i < TM; ++i) {
    int gr = row0 + trow * TM + i;
    if (gr >= M) continue;
    #pragma unroll
    for (int j = 0; j < TN; ++j) {
      int gc = col0 + tcol * TN + j;
      if (gc < N) C[(size_t)gr * N + gc] = acc[i][j];
    }
  }
}

// ---------------------------------------------------------------------------
// GAT: per-node attention scores s_src, s_dst (dot with att vectors)
__global__ void gat_sdots_kernel(const float* __restrict__ xwg,
                                 const float* __restrict__ att_src,
                                 const float* __restrict__ att_dst,
                                 float* __restrict__ s_src, float* __restrict__ s_dst, int n) {
  int gid = blockIdx.x * blockDim.x + threadIdx.x;
  int node = gid >> 5;
  int l = threadIdx.x & 31;
  if (node >= n) return;
  float v = xwg[(size_t)node * 32 + l];
  float vs = v * att_src[l];
  float vd = v * att_dst[l];
  #pragma unroll
  for (int m = 16; m >= 1; m >>= 1) {
    vs += __shfl_xor(vs, m);
    vd += __shfl_xor(vd, m);
  }
  if (l == 0) { s_src[node] = vs; s_dst[node] = vd; }
}

__device__ __forceinline__ float leaky02(float x) { return x > 0.f ? x : 0.2f * x; }

// GAT online-softmax aggregate + bias + ReLU + pooled partial accumulation.
// 64 threads = 2 softmax groups (lane>>5), alternate edges, shfl-combine.
__global__ __launch_bounds__(64) void gat_agg_kernel(
    const float* __restrict__ xwg, const float* __restrict__ s_src,
    const float* __restrict__ s_dst, const int* __restrict__ rowptr,
    const int* __restrict__ csr_src, const float* __restrict__ bg,
    float* __restrict__ pooled_part) {
  const int i = blockIdx.x;
  const int lane = threadIdx.x;
  const int f = lane & 31;
  const int half = lane >> 5;
  const float sd = s_dst[i];
  // group 0 takes the self loop; group 1 starts empty
  float m, den, acc;
  if (half == 0) {
    m = leaky02(s_src[i] + sd);
    den = 1.f;
    acc = xwg[(size_t)i * 32 + f];
  } else {
    m = -3.0e38f;
    den = 0.f;
    acc = 0.f;
  }
  const int beg = rowptr[i], end = rowptr[i + 1];
  for (int j = beg + half; j < end; j += 2) {
    int s = csr_src[j];
    float a = leaky02(s_src[s] + sd);
    float mn = fmaxf(m, a);
    float sc = __expf(m - mn);
    float ea = __expf(a - mn);
    acc = acc * sc + ea * xwg[(size_t)s * 32 + f];
    den = den * sc + ea;
    m = mn;
  }
  // combine the two groups
  float m_o = __shfl_xor(m, 32);
  float den_o = __shfl_xor(den, 32);
  float acc_o = __shfl_xor(acc, 32);
  float mn = fmaxf(m, m_o);
  float sc = __expf(m - mn);
  float so = __expf(m_o - mn);
  float den_t = den * sc + den_o * so;
  float acc_t = acc * sc + acc_o * so;
  float out = fmaxf(acc_t / den_t + bg[f], 0.f);
  if (lane < 32) atomicAdd(&pooled_part[(size_t)(i & (NPART - 1)) * 32 + f], out);
}

__global__ __launch_bounds__(64) void final_fc_kernel(const float* __restrict__ pooled_part,
                                                      const float* __restrict__ fc_w,
                                                      const float* __restrict__ fc_b,
                                                      float* __restrict__ out, float invN) {
  const int lane = threadIdx.x;
  const int f = lane & 31, half = lane >> 5;
  float p = 0.f;
  #pragma unroll
  for (int b = 0; b < NPART / 2; ++b)
    p += pooled_part[(size_t)(half * (NPART / 2) + b) * 32 + f];
  p += __shfl_xor(p, 32);
  p *= invN;
  #pragma unroll
  for (int c = 0; c < 2; ++c) {
    float v = (lane < 32) ? p * fc_w[f * 2 + c] : 0.f;
    #pragma unroll
    for (int m = 16; m >= 1; m >>= 1) v += __shfl_xor(v, m);
    if (lane == 0) out[c] = v + fc_b[c];
  }
}

// ---------------------------------------------------------------------------
extern "C" void kernel_launch(void* const* d_in, const int* in_sizes, int n_in,
                              void* d_out, int out_size, void* d_ws, size_t ws_size,
                              hipStream_t stream) {
  const float* x       = (const float*)d_in[0];
  const void*  edges   = d_in[1];
  const float* W1      = (const float*)d_in[2];
  const float* b1      = (const float*)d_in[3];
  const float* ln1_g   = (const float*)d_in[4];
  const float* ln1_b   = (const float*)d_in[5];
  const float* W2      = (const float*)d_in[6];
  const float* b2      = (const float*)d_in[7];
  const float* ln2_g   = (const float*)d_in[8];
  const float* ln2_b   = (const float*)d_in[9];
  const float* W3      = (const float*)d_in[10];
  const float* b3      = (const float*)d_in[11];
  const float* ln3_g   = (const float*)d_in[12];
  const float* ln3_b   = (const float*)d_in[13];
  const float* Wg      = (const float*)d_in[14];
  const float* att_src = (const float*)d_in[15];
  const float* att_dst = (const float*)d_in[16];
  const float* bg      = (const float*)d_in[17];
  const float* fc_w    = (const float*)d_in[18];
  const float* fc_b    = (const float*)d_in[19];
  float* out = (float*)d_out;

  const int N = N_NODES, E = N_EDGES;

  // workspace layout
  char* ws = (char*)d_ws;
  size_t off = 0;
  auto alloc = [&](size_t bytes) {
    size_t o = off;
    off = (off + bytes + 255) & ~(size_t)255;
    return o;
  };
  size_t o_bufA   = alloc((size_t)N * DIM_H1 * 4);
  size_t o_bufB   = alloc((size_t)N * DIM_H1 * 4);
  size_t o_w1t    = alloc((size_t)DIM_IN * DIM_H1 * 2);
  size_t o_w2t    = alloc((size_t)DIM_H1 * DIM_H2 * 2);
  size_t o_src    = alloc((size_t)E * 4);
  size_t o_dst    = alloc((size_t)E * 4);
  size_t o_csr    = alloc((size_t)E * 4);
  size_t o_cnt    = alloc((size_t)N * 4);
  size_t o_rowptr = alloc((size_t)(N + 1) * 4);
  size_t o_cursor = alloc((size_t)N * 4);
  size_t o_dinv   = alloc((size_t)N * 4);
  size_t o_ssrc   = alloc((size_t)N * 4);
  size_t o_sdst   = alloc((size_t)N * 4);
  size_t o_pooled = alloc((size_t)NPART * 32 * 4);
  size_t o_flag   = alloc(4);

  float* bufA   = (float*)(ws + o_bufA);
  float* bufB   = (float*)(ws + o_bufB);
  __bf16* W1T   = (__bf16*)(ws + o_w1t);
  __bf16* W2T   = (__bf16*)(ws + o_w2t);
  int*   srcI   = (int*)(ws + o_src);
  int*   dstI   = (int*)(ws + o_dst);
  int*   csr    = (int*)(ws + o_csr);
  int*   cnt    = (int*)(ws + o_cnt);
  int*   rowptr = (int*)(ws + o_rowptr);
  int*   cursor = (int*)(ws + o_cursor);
  float* dinv   = (float*)(ws + o_dinv);
  float* ssrc   = (float*)(ws + o_ssrc);
  float* sdst   = (float*)(ws + o_sdst);
  float* pooled = (float*)(ws + o_pooled);
  int*   flag   = (int*)(ws + o_flag);

  hipMemsetAsync(cnt, 0, (size_t)N * 4, stream);
  hipMemsetAsync(pooled, 0, (size_t)NPART * 32 * 4, stream);

  const int EB = (E + 255) / 256;

  // Graph preprocessing (CSR by dst, reused by all 4 conv layers)
  detect_fmt_kernel<<<1, 1, 0, stream>>>(edges, flag);
  convert_edges_kernel<<<EB, 256, 0, stream>>>(edges, flag, srcI, dstI, E);
  count_kernel<<<EB, 256, 0, stream>>>(dstI, cnt, E);
  scan_kernel<<<1, 1024, 0, stream>>>(cnt, rowptr, cursor, N);
  scatter_kernel<<<EB, 256, 0, stream>>>(srcI, dstI, cursor, csr, E);
  dinv_kernel<<<(N + 255) / 256, 256, 0, stream>>>(cnt, dinv, N);

  // Weight transposes (bf16 B^T operands for the MFMA GEMMs)
  transpose_cvt_kernel<<<dim3(DIM_IN / 32, DIM_H1 / 32), 256, 0, stream>>>(W1, W1T, DIM_IN, DIM_H1);
  transpose_cvt_kernel<<<dim3(DIM_H1 / 32, DIM_H2 / 32), 256, 0, stream>>>(W2, W2T, DIM_H1, DIM_H2);

  const int MB128 = (N + 127) / 128;  // 157
  const int MB64  = (N + 63) / 64;    // 313

  // Layer 1: xw1 = x @ W1 (64x128-tile MFMA, M-major grid, bf16 out)
  gemm64_kernel<float, __bf16>
      <<<dim3(MB64, DIM_H1 / 128), 256, 0, stream>>>(x, W1T, (__bf16*)bufA, N, DIM_H1, DIM_IN);
  gcn_agg_ln_relu_bf16_kernel<DIM_H1, 256>
      <<<N, 256, 0, stream>>>((const __bf16*)bufA, dinv, rowptr, csr, b1, ln1_g, ln1_b, (__bf16*)bufB);

  // Layer 2: xw2 = h1(bf16) @ W2 (fp32 out)
  gemm64_kernel<__bf16, float>
      <<<dim3(MB64, DIM_H2 / 128), 256, 0, stream>>>((const __bf16*)bufB, W2T, bufA, N, DIM_H2, DIM_H1);
  gcn_agg_ln_relu_kernel<DIM_H2, 128, float>
      <<<N, 128, 0, stream>>>(bufA, dinv, rowptr, csr, b2, ln2_g, ln2_b, bufB);

  // Layer 3: xw3 = h2 @ W3 (20000x128x32, tiny -> fp32 sgemm)
  sgemm_kernel<128, 32, 16, 8, 2>
      <<<dim3(1, MB128), 256, 0, stream>>>(bufB, W3, bufA, N, DIM_H3, DIM_H2);
  gcn_agg_ln_relu_kernel<DIM_H3, 64, float>
      <<<N, 64, 0, stream>>>(bufA, dinv, rowptr, csr, b3, ln3_g, ln3_b, bufB);

  // GAT: xwg = h3 @ Wg (20000x32x32)
  sgemm_kernel<128, 32, 16, 8, 2>
      <<<dim3(1, MB128), 256, 0, stream>>>(bufB, Wg, bufA, N, DIM_H3, DIM_H3);
  gat_sdots_kernel<<<(N * 32 + 255) / 256, 256, 0, stream>>>(bufA, att_src, att_dst, ssrc, sdst, N);
  gat_agg_kernel<<<N, 64, 0, stream>>>(bufA, ssrc, sdst, rowptr, csr, bg, pooled);

  final_fc_kernel<<<1, 64, 0, stream>>>(pooled, fc_w, fc_b, out, 1.f / (float)N);
}

// Round 6
// 393.151 us; speedup vs baseline: 1.1921x; 1.0599x over previous
//
#include <hip/hip_runtime.h>
#include <hip/hip_bf16.h>
#include <cstdint>
#include <cstddef>

// Problem constants (match reference setup_inputs)
#define N_NODES 20000
#define N_EDGES 320000
#define DIM_IN  2048
#define DIM_H1  512
#define DIM_H2  128
#define DIM_H3  32
#define NPART   64   // pooled partial buffers
static constexpr float LN_EPS = 1e-5f;

typedef __bf16 bf16x8 __attribute__((ext_vector_type(8)));
typedef __bf16 bf16x2 __attribute__((ext_vector_type(2)));
typedef float f32x4 __attribute__((ext_vector_type(4)));

// global -> LDS 16B async DMA. LDS dest is WAVE-UNIFORM base; HW writes
// lane i at base + i*16B. Global src IS per-lane (m104/m173).
__device__ __forceinline__ void glds16(const void* g, void* l) {
  __builtin_amdgcn_global_load_lds(
      (const __attribute__((address_space(1))) unsigned int*)g,
      (__attribute__((address_space(3))) unsigned int*)l, 16, 0, 0);
}

// ---------------------------------------------------------------------------
// Edge dtype detection: reference says int64, but JAX default (x64 disabled)
// downcasts to int32. If int64: viewing as int2, every .y is 0 (values in
// [0,20000)). If int32: .y are random node ids -> P(all 32 zero) ~ 0.
__global__ void detect_fmt_kernel(const void* eraw, int* flag) {
  const int2* p = (const int2*)eraw;
  int all0 = 1;
  for (int i = 0; i < 32; ++i) if (p[i].y != 0) all0 = 0;
  *flag = all0;  // 1 => int64 layout
}

__global__ void convert_edges_kernel(const void* eraw, const int* __restrict__ flag,
                                     int* __restrict__ src, int* __restrict__ dst, int E) {
  const int is64 = *flag;
  for (int e = blockIdx.x * blockDim.x + threadIdx.x; e < E; e += gridDim.x * blockDim.x) {
    if (is64) {
      const long long* p = (const long long*)eraw;
      src[e] = (int)p[e];
      dst[e] = (int)p[(size_t)E + e];
    } else {
      const int* p = (const int*)eraw;
      src[e] = p[e];
      dst[e] = p[(size_t)E + e];
    }
  }
}

__global__ void count_kernel(const int* __restrict__ dst, int* __restrict__ cnt, int E) {
  for (int e = blockIdx.x * blockDim.x + threadIdx.x; e < E; e += gridDim.x * blockDim.x)
    atomicAdd(&cnt[dst[e]], 1);
}

// Exclusive prefix sum of cnt[0..n) -> rowptr[0..n], cursor copy. One block.
__global__ __launch_bounds__(1024) void scan_kernel(const int* __restrict__ cnt,
                                                    int* __restrict__ rowptr,
                                                    int* __restrict__ cursor, int n) {
  __shared__ int s[1024];
  const int t = threadIdx.x;
  const int chunk = (n + 1023) / 1024;
  const int beg = t * chunk;
  const int end = min(beg + chunk, n);
  int sum = 0;
  for (int i = beg; i < end; ++i) sum += cnt[i];
  s[t] = sum;
  __syncthreads();
  for (int d = 1; d < 1024; d <<= 1) {
    int v = (t >= d) ? s[t - d] : 0;
    __syncthreads();
    s[t] += v;
    __syncthreads();
  }
  int run = s[t] - sum;  // exclusive prefix of this thread's chunk
  for (int i = beg; i < end; ++i) { rowptr[i] = run; cursor[i] = run; run += cnt[i]; }
  if (t == 1023) rowptr[n] = s[1023];
}

__global__ void scatter_kernel(const int* __restrict__ src, const int* __restrict__ dst,
                               int* __restrict__ cursor, int* __restrict__ csr_src, int E) {
  for (int e = blockIdx.x * blockDim.x + threadIdx.x; e < E; e += gridDim.x * blockDim.x) {
    int d = dst[e];
    int pos = atomicAdd(&cursor[d], 1);
    csr_src[pos] = src[e];
  }
}

__global__ void dinv_kernel(const int* __restrict__ cnt, float* __restrict__ dinv, int n) {
  int i = blockIdx.x * blockDim.x + threadIdx.x;
  if (i < n) dinv[i] = rsqrtf((float)(cnt[i] + 1));  // +1 self loop; always >= 1
}

// ---------------------------------------------------------------------------
// W[K][N] fp32 -> WT[N][K] bf16 (for MFMA B^T operand). K,N multiples of 32.
__global__ __launch_bounds__(256) void transpose_cvt_kernel(const float* __restrict__ W,
                                                            __bf16* __restrict__ WT,
                                                            int K, int N) {
  __shared__ float t[32][33];
  const int kb = blockIdx.x * 32, nb = blockIdx.y * 32;
  const int tx = threadIdx.x & 31, ty = threadIdx.x >> 5;  // ty: 0..7
  #pragma unroll
  for (int i = 0; i < 32; i += 8)
    t[ty + i][tx] = W[(size_t)(kb + ty + i) * N + nb + tx];
  __syncthreads();
  #pragma unroll
  for (int i = 0; i < 32; i += 8)
    WT[(size_t)(nb + ty + i) * K + kb + tx] = (__bf16)t[tx][ty + i];
}

// ---------------------------------------------------------------------------
// m97-structure MFMA GEMM: C[M][N] = A[M][K] @ BT[N][K]^T.
// 128x128 tile, BK=32, 4 waves x 64x64 (4x4 frags) = 16 MFMA/wave/K-step.
// Staging via global_load_lds (linear LDS dest). Bank-conflict-free frag
// reads via BOTH-sides swizzle (m173/m201): per-lane pre-swizzled global
// source slot + same XOR on the ds_read slot; LDS dest stays linear.
//   A fp32 (16KB LDS, 128B rows, 8 slots):  slot' = slot ^ (row&7)
//   A/B bf16 (8KB LDS, 64B rows, 4 slots):  slot' = slot ^ ((row>>1)&3)
// fp32 A frags are cvt'd to bf16 at read (VALU overlaps MFMA, m114).
// Grid: (Mtiles, N/128). N%128==0, K%32==0; M edge clamp/guard.
template <typename AT, typename CT>
__global__ __launch_bounds__(256) void gemm_glds_kernel(
    const AT* __restrict__ A, const __bf16* __restrict__ BT,
    CT* __restrict__ C, int M, int N, int K) {
  __shared__ __align__(16) AT     Asm[128 * 32];
  __shared__ __align__(16) __bf16 Bsm[128 * 32];
  const int tid = threadIdx.x;
  const int wave = tid >> 6;
  const int lane = tid & 63;
  const int row0 = blockIdx.x * 128;
  const int col0 = blockIdx.y * 128;
  const int wr = (wave >> 1) * 64;
  const int wc = (wave & 1) * 64;

  f32x4 acc[4][4] = {};

  for (int k0 = 0; k0 < K; k0 += 32) {
    // ---- stage A ----
    if constexpr (sizeof(AT) == 4) {
      // fp32: 1024B/issue = 8 rows; lane -> (row=lane>>3, slot=lane&7 of 16B)
      // source slot pre-swizzled: slot_src = (lane&7) ^ (lane>>3)  [row&7]
      #pragma unroll
      for (int i = 0; i < 4; ++i) {
        const int rbase = wave * 32 + i * 8;
        int gr = row0 + rbase + (lane >> 3);
        if (gr >= M) gr = M - 1;
        const int ssrc = (lane & 7) ^ (lane >> 3);
        glds16((const float*)A + (size_t)gr * K + k0 + ssrc * 4, &Asm[rbase * 32]);
      }
    } else {
      // bf16: 1024B/issue = 16 rows; lane -> (row=lane>>2, slot=lane&3)
      // slot_src = (lane&3) ^ ((lane>>3)&3)   [(row>>1)&3]
      #pragma unroll
      for (int i = 0; i < 2; ++i) {
        const int rbase = wave * 32 + i * 16;
        int gr = row0 + rbase + (lane >> 2);
        if (gr >= M) gr = M - 1;
        const int ssrc = (lane & 3) ^ ((lane >> 3) & 3);
        glds16((const __bf16*)A + (size_t)gr * K + k0 + ssrc * 8, &Asm[rbase * 32]);
      }
    }
    // ---- stage B (bf16) ----
    #pragma unroll
    for (int j = 0; j < 2; ++j) {
      const int rbase = wave * 32 + j * 16;
      const int gr = col0 + rbase + (lane >> 2);
      const int ssrc = (lane & 3) ^ ((lane >> 3) & 3);
      glds16(BT + (size_t)gr * K + k0 + ssrc * 8, &Bsm[rbase * 32]);
    }
    __syncthreads();  // compiler drains vmcnt before barrier

    // ---- fragments ----
    const int q = lane >> 4;
    bf16x8 af[4], bfr[4];
    #pragma unroll
    for (int m = 0; m < 4; ++m) {
      const int row = wr + m * 16 + (lane & 15);
      if constexpr (sizeof(AT) == 4) {
        const int sw = row & 7;
        f32x4 lo = *(const f32x4*)&((const float*)Asm)[row * 32 + (((2 * q) ^ sw) * 4)];
        f32x4 hi = *(const f32x4*)&((const float*)Asm)[row * 32 + (((2 * q + 1) ^ sw) * 4)];
        bf16x8 o;
        o[0] = (__bf16)lo[0]; o[1] = (__bf16)lo[1]; o[2] = (__bf16)lo[2]; o[3] = (__bf16)lo[3];
        o[4] = (__bf16)hi[0]; o[5] = (__bf16)hi[1]; o[6] = (__bf16)hi[2]; o[7] = (__bf16)hi[3];
        af[m] = o;
      } else {
        const int sw = (row >> 1) & 3;
        af[m] = *(const bf16x8*)&((const __bf16*)Asm)[row * 32 + ((q ^ sw) * 8)];
      }
    }
    #pragma unroll
    for (int n = 0; n < 4; ++n) {
      const int row = wc + n * 16 + (lane & 15);
      const int sw = (row >> 1) & 3;
      bfr[n] = *(const bf16x8*)&Bsm[row * 32 + ((q ^ sw) * 8)];
    }
    #pragma unroll
    for (int m = 0; m < 4; ++m)
      #pragma unroll
      for (int n = 0; n < 4; ++n)
        acc[m][n] = __builtin_amdgcn_mfma_f32_16x16x32_bf16(af[m], bfr[n], acc[m][n], 0, 0, 0);
    __syncthreads();
  }

  // Epilogue: D layout col=lane&15, row=(lane>>4)*4+j (m89-verified)
  #pragma unroll
  for (int m = 0; m < 4; ++m) {
    const int r = row0 + wr + m * 16 + (lane >> 4) * 4;
    #pragma unroll
    for (int n = 0; n < 4; ++n) {
      const int c = col0 + wc + n * 16 + (lane & 15);
      #pragma unroll
      for (int j = 0; j < 4; ++j)
        if (r + j < M) C[(size_t)(r + j) * N + c] = (CT)acc[m][n][j];
    }
  }
}

// ---------------------------------------------------------------------------
// Fused GCN aggregate + bias + LayerNorm + ReLU (fp32 xw input).
template <int F, int TPB, typename OutT>
__global__ __launch_bounds__(TPB) void gcn_agg_ln_relu_kernel(
    const float* __restrict__ xw, const float* __restrict__ dinv,
    const int* __restrict__ rowptr, const int* __restrict__ csr_src,
    const float* __restrict__ bias, const float* __restrict__ gamma,
    const float* __restrict__ beta, OutT* __restrict__ h) {
  constexpr int NF = (F + TPB - 1) / TPB;
  const int i = blockIdx.x;
  const int tid = threadIdx.x;
  const float di = dinv[i];
  float acc[NF];
  #pragma unroll
  for (int q = 0; q < NF; ++q) {
    int f = tid + q * TPB;
    acc[q] = (f < F) ? di * xw[(size_t)i * F + f] : 0.f;  // self loop
  }
  const int beg = rowptr[i], end = rowptr[i + 1];
  for (int j = beg; j < end; ++j) {
    int s = csr_src[j];
    float c = dinv[s];
    const float* row = xw + (size_t)s * F;
    #pragma unroll
    for (int q = 0; q < NF; ++q) {
      int f = tid + q * TPB;
      if (f < F) acc[q] += c * row[f];
    }
  }
  float sum = 0.f, sumsq = 0.f;
  #pragma unroll
  for (int q = 0; q < NF; ++q) {
    int f = tid + q * TPB;
    if (f < F) {
      float v = di * acc[q] + bias[f];
      acc[q] = v;
      sum += v;
      sumsq += v * v;
    }
  }
  #pragma unroll
  for (int m = 32; m >= 1; m >>= 1) {
    sum += __shfl_xor(sum, m);
    sumsq += __shfl_xor(sumsq, m);
  }
  constexpr int NW = TPB / 64;
  __shared__ float red[2][NW];
  const int wid = tid >> 6, lane = tid & 63;
  if (lane == 0) { red[0][wid] = sum; red[1][wid] = sumsq; }
  __syncthreads();
  if (tid == 0) {
    float a = 0.f, b2 = 0.f;
    for (int w = 0; w < NW; ++w) { a += red[0][w]; b2 += red[1][w]; }
    red[0][0] = a;
    red[1][0] = b2;
  }
  __syncthreads();
  const float mu = red[0][0] / F;
  const float var = red[1][0] / F - mu * mu;
  const float rstd = rsqrtf(var + LN_EPS);
  #pragma unroll
  for (int q = 0; q < NF; ++q) {
    int f = tid + q * TPB;
    if (f < F) h[(size_t)i * F + f] = (OutT)fmaxf(0.f, (acc[q] - mu) * rstd * gamma[f] + beta[f]);
  }
}

// bf16-input variant: each thread owns 2 consecutive features (one 4B load
// per neighbor row -> coalesced). F == 2*TPB. fp32 accumulate, OutT out.
template <int F, int TPB, typename OutT>
__global__ __launch_bounds__(TPB) void gcn_agg_ln_relu_bf16_kernel(
    const __bf16* __restrict__ xw, const float* __restrict__ dinv,
    const int* __restrict__ rowptr, const int* __restrict__ csr_src,
    const float* __restrict__ bias, const float* __restrict__ gamma,
    const float* __restrict__ beta, OutT* __restrict__ h) {
  static_assert(F == 2 * TPB, "layout");
  const int i = blockIdx.x;
  const int tid = threadIdx.x;
  const int f0 = tid * 2;
  const float di = dinv[i];
  bf16x2 v = *(const bf16x2*)&xw[(size_t)i * F + f0];
  float a0 = di * (float)v[0];
  float a1 = di * (float)v[1];
  const int beg = rowptr[i], end = rowptr[i + 1];
  for (int j = beg; j < end; ++j) {
    int s = csr_src[j];
    float c = dinv[s];
    bf16x2 r = *(const bf16x2*)&xw[(size_t)s * F + f0];
    a0 += c * (float)r[0];
    a1 += c * (float)r[1];
  }
  a0 = di * a0 + bias[f0];
  a1 = di * a1 + bias[f0 + 1];
  float sum = a0 + a1;
  float sumsq = a0 * a0 + a1 * a1;
  #pragma unroll
  for (int m = 32; m >= 1; m >>= 1) {
    sum += __shfl_xor(sum, m);
    sumsq += __shfl_xor(sumsq, m);
  }
  constexpr int NW = TPB / 64;
  __shared__ float red[2][NW];
  const int wid = tid >> 6, lane = tid & 63;
  if (lane == 0) { red[0][wid] = sum; red[1][wid] = sumsq; }
  __syncthreads();
  if (tid == 0) {
    float a = 0.f, b2 = 0.f;
    for (int w = 0; w < NW; ++w) { a += red[0][w]; b2 += red[1][w]; }
    red[0][0] = a;
    red[1][0] = b2;
  }
  __syncthreads();
  const float mu = red[0][0] / F;
  const float var = red[1][0] / F - mu * mu;
  const float rstd = rsqrtf(var + LN_EPS);
  float o0 = fmaxf(0.f, (a0 - mu) * rstd * gamma[f0] + beta[f0]);
  float o1 = fmaxf(0.f, (a1 - mu) * rstd * gamma[f0 + 1] + beta[f0 + 1]);
  if constexpr (sizeof(OutT) == 2) {
    bf16x2 o; o[0] = (__bf16)o0; o[1] = (__bf16)o1;
    *(bf16x2*)&((__bf16*)h)[(size_t)i * F + f0] = o;
  } else {
    float2 o = make_float2(o0, o1);
    *(float2*)&((float*)h)[(size_t)i * F + f0] = o;
  }
}

// ---------------------------------------------------------------------------
// fp32 tiled GEMM (kept for the tiny GEMM3 / GAT-GEMM). 256 threads.
template <int BM, int BN, int BK, int TM, int TN>
__global__ __launch_bounds__((BM / TM) * (BN / TN)) void sgemm_kernel(
    const float* __restrict__ A, const float* __restrict__ B, float* __restrict__ C,
    int M, int N, int K) {
  constexpr int THREADS = (BM / TM) * (BN / TN);
  __shared__ float As[BK][BM + 4];
  __shared__ float Bs[BK][BN];
  const int tid = threadIdx.x;
  const int tcol = tid % (BN / TN);
  const int trow = tid / (BN / TN);
  const int row0 = blockIdx.y * BM;
  const int col0 = blockIdx.x * BN;
  float acc[TM][TN] = {};
  for (int k0 = 0; k0 < K; k0 += BK) {
    constexpr int A4 = BM * BK / 4;
    #pragma unroll
    for (int i = tid; i < A4; i += THREADS) {
      int r = i / (BK / 4);
      int c4 = i % (BK / 4);
      int gr = row0 + r;
      float4 v = make_float4(0.f, 0.f, 0.f, 0.f);
      if (gr < M) v = *(const float4*)(A + (size_t)gr * K + k0 + c4 * 4);
      As[c4 * 4 + 0][r] = v.x;
      As[c4 * 4 + 1][r] = v.y;
      As[c4 * 4 + 2][r] = v.z;
      As[c4 * 4 + 3][r] = v.w;
    }
    constexpr int B4 = BK * BN / 4;
    #pragma unroll
    for (int i = tid; i < B4; i += THREADS) {
      int r = i / (BN / 4);
      int c4 = i % (BN / 4);
      float4 v = *(const float4*)(B + (size_t)(k0 + r) * N + col0 + c4 * 4);
      *(float4*)(&Bs[r][c4 * 4]) = v;
    }
    __syncthreads();
    #pragma unroll
    for (int kk = 0; kk < BK; ++kk) {
      float ra[TM], rb[TN];
      #pragma unroll
      for (int i = 0; i < TM; ++i) ra[i] = As[kk][trow * TM + i];
      #pragma unroll
      for (int j = 0; j < TN; ++j) rb[j] = Bs[kk][tcol * TN + j];
      #pragma unroll
      for (int i = 0; i < TM; ++i)
        #pragma unroll
        for (int j = 0; j < TN; ++j) acc[i][j] = fmaf(ra[i], rb[j], acc[i][j]);
    }
    __syncthreads();
  }
  #pragma unroll
  for (int i = 0; i < TM; ++i) {
    int gr = row0 + trow * TM + i;
    if (gr >= M) continue;
    #pragma unroll
    for (int j = 0; j < TN; ++j) {
      int gc = col0 + tcol * TN + j;
      if (gc < N) C[(size_t)gr * N + gc] = acc[i][j];
    }
  }
}

// ---------------------------------------------------------------------------
// GAT: per-node attention scores s_src, s_dst (dot with att vectors)
__global__ void gat_sdots_kernel(const float* __restrict__ xwg,
                                 const float* __restrict__ att_src,
                                 const float* __restrict__ att_dst,
                                 float* __restrict__ s_src, float* __restrict__ s_dst, int n) {
  int gid = blockIdx.x * blockDim.x + threadIdx.x;
  int node = gid >> 5;
  int l = threadIdx.x & 31;
  if (node >= n) return;
  float v = xwg[(size_t)node * 32 + l];
  float vs = v * att_src[l];
  float vd = v * att_dst[l];
  #pragma unroll
  for (int m = 16; m >= 1; m >>= 1) {
    vs += __shfl_xor(vs, m);
    vd += __shfl_xor(vd, m);
  }
  if (l == 0) { s_src[node] = vs; s_dst[node] = vd; }
}

__device__ __forceinline__ float leaky02(float x) { return x > 0.f ? x : 0.2f * x; }

// GAT online-softmax aggregate + bias + ReLU + pooled partial accumulation.
// 64 threads = 2 softmax groups (lane>>5), alternate edges, shfl-combine.
__global__ __launch_bounds__(64) void gat_agg_kernel(
    const float* __restrict__ xwg, const float* __restrict__ s_src,
    const float* __restrict__ s_dst, const int* __restrict__ rowptr,
    const int* __restrict__ csr_src, const float* __restrict__ bg,
    float* __restrict__ pooled_part) {
  const int i = blockIdx.x;
  const int lane = threadIdx.x;
  const int f = lane & 31;
  const int half = lane >> 5;
  const float sd = s_dst[i];
  // group 0 takes the self loop; group 1 starts empty
  float m, den, acc;
  if (half == 0) {
    m = leaky02(s_src[i] + sd);
    den = 1.f;
    acc = xwg[(size_t)i * 32 + f];
  } else {
    m = -3.0e38f;
    den = 0.f;
    acc = 0.f;
  }
  const int beg = rowptr[i], end = rowptr[i + 1];
  for (int j = beg + half; j < end; j += 2) {
    int s = csr_src[j];
    float a = leaky02(s_src[s] + sd);
    float mn = fmaxf(m, a);
    float sc = __expf(m - mn);
    float ea = __expf(a - mn);
    acc = acc * sc + ea * xwg[(size_t)s * 32 + f];
    den = den * sc + ea;
    m = mn;
  }
  // combine the two groups
  float m_o = __shfl_xor(m, 32);
  float den_o = __shfl_xor(den, 32);
  float acc_o = __shfl_xor(acc, 32);
  float mn = fmaxf(m, m_o);
  float sc = __expf(m - mn);
  float so = __expf(m_o - mn);
  float den_t = den * sc + den_o * so;
  float acc_t = acc * sc + acc_o * so;
  float out = fmaxf(acc_t / den_t + bg[f], 0.f);
  if (lane < 32) atomicAdd(&pooled_part[(size_t)(i & (NPART - 1)) * 32 + f], out);
}

__global__ __launch_bounds__(64) void final_fc_kernel(const float* __restrict__ pooled_part,
                                                      const float* __restrict__ fc_w,
                                                      const float* __restrict__ fc_b,
                                                      float* __restrict__ out, float invN) {
  const int lane = threadIdx.x;
  const int f = lane & 31, half = lane >> 5;
  float p = 0.f;
  #pragma unroll
  for (int b = 0; b < NPART / 2; ++b)
    p += pooled_part[(size_t)(half * (NPART / 2) + b) * 32 + f];
  p += __shfl_xor(p, 32);
  p *= invN;
  #pragma unroll
  for (int c = 0; c < 2; ++c) {
    float v = (lane < 32) ? p * fc_w[f * 2 + c] : 0.f;
    #pragma unroll
    for (int m = 16; m >= 1; m >>= 1) v += __shfl_xor(v, m);
    if (lane == 0) out[c] = v + fc_b[c];
  }
}

// ---------------------------------------------------------------------------
extern "C" void kernel_launch(void* const* d_in, const int* in_sizes, int n_in,
                              void* d_out, int out_size, void* d_ws, size_t ws_size,
                              hipStream_t stream) {
  const float* x       = (const float*)d_in[0];
  const void*  edges   = d_in[1];
  const float* W1      = (const float*)d_in[2];
  const float* b1      = (const float*)d_in[3];
  const float* ln1_g   = (const float*)d_in[4];
  const float* ln1_b   = (const float*)d_in[5];
  const float* W2      = (const float*)d_in[6];
  const float* b2      = (const float*)d_in[7];
  const float* ln2_g   = (const float*)d_in[8];
  const float* ln2_b   = (const float*)d_in[9];
  const float* W3      = (const float*)d_in[10];
  const float* b3      = (const float*)d_in[11];
  const float* ln3_g   = (const float*)d_in[12];
  const float* ln3_b   = (const float*)d_in[13];
  const float* Wg      = (const float*)d_in[14];
  const float* att_src = (const float*)d_in[15];
  const float* att_dst = (const float*)d_in[16];
  const float* bg      = (const float*)d_in[17];
  const float* fc_w    = (const float*)d_in[18];
  const float* fc_b    = (const float*)d_in[19];
  float* out = (float*)d_out;

  const int N = N_NODES, E = N_EDGES;

  // workspace layout
  char* ws = (char*)d_ws;
  size_t off = 0;
  auto alloc = [&](size_t bytes) {
    size_t o = off;
    off = (off + bytes + 255) & ~(size_t)255;
    return o;
  };
  size_t o_bufA   = alloc((size_t)N * DIM_H1 * 4);
  size_t o_bufB   = alloc((size_t)N * DIM_H1 * 4);
  size_t o_w1t    = alloc((size_t)DIM_IN * DIM_H1 * 2);
  size_t o_w2t    = alloc((size_t)DIM_H1 * DIM_H2 * 2);
  size_t o_src    = alloc((size_t)E * 4);
  size_t o_dst    = alloc((size_t)E * 4);
  size_t o_csr    = alloc((size_t)E * 4);
  size_t o_cnt    = alloc((size_t)N * 4);
  size_t o_rowptr = alloc((size_t)(N + 1) * 4);
  size_t o_cursor = alloc((size_t)N * 4);
  size_t o_dinv   = alloc((size_t)N * 4);
  size_t o_ssrc   = alloc((size_t)N * 4);
  size_t o_sdst   = alloc((size_t)N * 4);
  size_t o_pooled = alloc((size_t)NPART * 32 * 4);
  size_t o_flag   = alloc(4);

  float* bufA   = (float*)(ws + o_bufA);
  float* bufB   = (float*)(ws + o_bufB);
  __bf16* W1T   = (__bf16*)(ws + o_w1t);
  __bf16* W2T   = (__bf16*)(ws + o_w2t);
  int*   srcI   = (int*)(ws + o_src);
  int*   dstI   = (int*)(ws + o_dst);
  int*   csr    = (int*)(ws + o_csr);
  int*   cnt    = (int*)(ws + o_cnt);
  int*   rowptr = (int*)(ws + o_rowptr);
  int*   cursor = (int*)(ws + o_cursor);
  float* dinv   = (float*)(ws + o_dinv);
  float* ssrc   = (float*)(ws + o_ssrc);
  float* sdst   = (float*)(ws + o_sdst);
  float* pooled = (float*)(ws + o_pooled);
  int*   flag   = (int*)(ws + o_flag);

  hipMemsetAsync(cnt, 0, (size_t)N * 4, stream);
  hipMemsetAsync(pooled, 0, (size_t)NPART * 32 * 4, stream);

  const int EB = (E + 255) / 256;

  // Graph preprocessing (CSR by dst, reused by all 4 conv layers)
  detect_fmt_kernel<<<1, 1, 0, stream>>>(edges, flag);
  convert_edges_kernel<<<EB, 256, 0, stream>>>(edges, flag, srcI, dstI, E);
  count_kernel<<<EB, 256, 0, stream>>>(dstI, cnt, E);
  scan_kernel<<<1, 1024, 0, stream>>>(cnt, rowptr, cursor, N);
  scatter_kernel<<<EB, 256, 0, stream>>>(srcI, dstI, cursor, csr, E);
  dinv_kernel<<<(N + 255) / 256, 256, 0, stream>>>(cnt, dinv, N);

  // Weight transposes (bf16 B^T operands for the MFMA GEMMs)
  transpose_cvt_kernel<<<dim3(DIM_IN / 32, DIM_H1 / 32), 256, 0, stream>>>(W1, W1T, DIM_IN, DIM_H1);
  transpose_cvt_kernel<<<dim3(DIM_H1 / 32, DIM_H2 / 32), 256, 0, stream>>>(W2, W2T, DIM_H1, DIM_H2);

  const int MB128 = (N + 127) / 128;  // 157

  // Layer 1: xw1 = x @ W1 (m97-structure MFMA, global_load_lds, bf16 out)
  gemm_glds_kernel<float, __bf16>
      <<<dim3(MB128, DIM_H1 / 128), 256, 0, stream>>>(x, W1T, (__bf16*)bufA, N, DIM_H1, DIM_IN);
  gcn_agg_ln_relu_bf16_kernel<DIM_H1, 256, __bf16>
      <<<N, 256, 0, stream>>>((const __bf16*)bufA, dinv, rowptr, csr, b1, ln1_g, ln1_b, (__bf16*)bufB);

  // Layer 2: xw2 = h1(bf16) @ W2 (bf16 out -> halves agg2 gather traffic)
  gemm_glds_kernel<__bf16, __bf16>
      <<<dim3(MB128, DIM_H2 / 128), 256, 0, stream>>>((const __bf16*)bufB, W2T, (__bf16*)bufA, N, DIM_H2, DIM_H1);
  gcn_agg_ln_relu_bf16_kernel<DIM_H2, 64, float>
      <<<N, 64, 0, stream>>>((const __bf16*)bufA, dinv, rowptr, csr, b2, ln2_g, ln2_b, bufB);

  // Layer 3: xw3 = h2 @ W3 (20000x128x32, tiny -> fp32 sgemm)
  sgemm_kernel<128, 32, 16, 8, 2>
      <<<dim3(1, MB128), 256, 0, stream>>>(bufB, W3, bufA, N, DIM_H3, DIM_H2);
  gcn_agg_ln_relu_kernel<DIM_H3, 64, float>
      <<<N, 64, 0, stream>>>(bufA, dinv, rowptr, csr, b3, ln3_g, ln3_b, bufB);

  // GAT: xwg = h3 @ Wg (20000x32x32)
  sgemm_kernel<128, 32, 16, 8, 2>
      <<<dim3(1, MB128), 256, 0, stream>>>(bufB, Wg, bufA, N, DIM_H3, DIM_H3);
  gat_sdots_kernel<<<(N * 32 + 255) / 256, 256, 0, stream>>>(bufA, att_src, att_dst, ssrc, sdst, N);
  gat_agg_kernel<<<N, 64, 0, stream>>>(bufA, ssrc, sdst, rowptr, csr, bg, pooled);

  final_fc_kernel<<<1, 64, 0, stream>>>(pooled, fc_w, fc_b, out, 1.f / (float)N);
}

// Round 7
// 390.128 us; speedup vs baseline: 1.2014x; 1.0077x over previous
//
#include <hip/hip_runtime.h>
#include <hip/hip_bf16.h>
#include <cstdint>
#include <cstddef>

// Problem constants (match reference setup_inputs)
#define N_NODES 20000
#define N_EDGES 320000
#define DIM_IN  2048
#define DIM_H1  512
#define DIM_H2  128
#define DIM_H3  32
#define NPART   64   // pooled partial buffers
static constexpr float LN_EPS = 1e-5f;

typedef __bf16 bf16x8 __attribute__((ext_vector_type(8)));
typedef __bf16 bf16x2 __attribute__((ext_vector_type(2)));
typedef float f32x4 __attribute__((ext_vector_type(4)));

// global -> LDS 16B async DMA. LDS dest is WAVE-UNIFORM base; HW writes
// lane i at base + i*16B. Global src IS per-lane (m104/m173).
__device__ __forceinline__ void glds16(const void* g, void* l) {
  __builtin_amdgcn_global_load_lds(
      (const __attribute__((address_space(1))) unsigned int*)g,
      (__attribute__((address_space(3))) unsigned int*)l, 16, 0, 0);
}

// ---------------------------------------------------------------------------
// Edge dtype detection: reference says int64, but JAX default (x64 disabled)
// downcasts to int32. If int64: viewing as int2, every .y is 0 (values in
// [0,20000)). If int32: .y are random node ids -> P(all 32 zero) ~ 0.
__global__ void detect_fmt_kernel(const void* eraw, int* flag) {
  const int2* p = (const int2*)eraw;
  int all0 = 1;
  for (int i = 0; i < 32; ++i) if (p[i].y != 0) all0 = 0;
  *flag = all0;  // 1 => int64 layout
}

// Also counts in-degree (fused former count_kernel).
__global__ void convert_edges_kernel(const void* eraw, const int* __restrict__ flag,
                                     int* __restrict__ src, int* __restrict__ dst,
                                     int* __restrict__ cnt, int E) {
  const int is64 = *flag;
  for (int e = blockIdx.x * blockDim.x + threadIdx.x; e < E; e += gridDim.x * blockDim.x) {
    int s, d;
    if (is64) {
      const long long* p = (const long long*)eraw;
      s = (int)p[e];
      d = (int)p[(size_t)E + e];
    } else {
      const int* p = (const int*)eraw;
      s = p[e];
      d = p[(size_t)E + e];
    }
    src[e] = s;
    dst[e] = d;
    atomicAdd(&cnt[d], 1);
  }
}

// Exclusive prefix sum of cnt[0..n) -> rowptr[0..n], cursor copy. One block.
__global__ __launch_bounds__(1024) void scan_kernel(const int* __restrict__ cnt,
                                                    int* __restrict__ rowptr,
                                                    int* __restrict__ cursor, int n) {
  __shared__ int s[1024];
  const int t = threadIdx.x;
  const int chunk = (n + 1023) / 1024;
  const int beg = t * chunk;
  const int end = min(beg + chunk, n);
  int sum = 0;
  for (int i = beg; i < end; ++i) sum += cnt[i];
  s[t] = sum;
  __syncthreads();
  for (int d = 1; d < 1024; d <<= 1) {
    int v = (t >= d) ? s[t - d] : 0;
    __syncthreads();
    s[t] += v;
    __syncthreads();
  }
  int run = s[t] - sum;  // exclusive prefix of this thread's chunk
  for (int i = beg; i < end; ++i) { rowptr[i] = run; cursor[i] = run; run += cnt[i]; }
  if (t == 1023) rowptr[n] = s[1023];
}

__global__ void scatter_kernel(const int* __restrict__ src, const int* __restrict__ dst,
                               int* __restrict__ cursor, int* __restrict__ csr_src, int E) {
  for (int e = blockIdx.x * blockDim.x + threadIdx.x; e < E; e += gridDim.x * blockDim.x) {
    int d = dst[e];
    int pos = atomicAdd(&cursor[d], 1);
    csr_src[pos] = src[e];
  }
}

__global__ void dinv_kernel(const int* __restrict__ cnt, float* __restrict__ dinv, int n) {
  int i = blockIdx.x * blockDim.x + threadIdx.x;
  if (i < n) dinv[i] = rsqrtf((float)(cnt[i] + 1));  // +1 self loop; always >= 1
}

// ---------------------------------------------------------------------------
// W[K][N] fp32 -> WT[N][K] bf16 (for MFMA B^T operand). K,N multiples of 32.
__global__ __launch_bounds__(256) void transpose_cvt_kernel(const float* __restrict__ W,
                                                            __bf16* __restrict__ WT,
                                                            int K, int N) {
  __shared__ float t[32][33];
  const int kb = blockIdx.x * 32, nb = blockIdx.y * 32;
  const int tx = threadIdx.x & 31, ty = threadIdx.x >> 5;  // ty: 0..7
  #pragma unroll
  for (int i = 0; i < 32; i += 8)
    t[ty + i][tx] = W[(size_t)(kb + ty + i) * N + nb + tx];
  __syncthreads();
  #pragma unroll
  for (int i = 0; i < 32; i += 8)
    WT[(size_t)(nb + ty + i) * K + kb + tx] = (__bf16)t[tx][ty + i];
}

// ---------------------------------------------------------------------------
// Double-buffered m97-structure MFMA GEMM (T3 minimum 2-phase recipe):
// per iter: STAGE(next) -> vmcnt(NGLDS, counted: next's loads stay in
// flight) -> s_barrier -> ds_read+MFMA(cur) -> s_barrier. Raw barriers +
// sched_barrier(0) so the compiler cannot insert a vmcnt(0) drain.
// 128x128 tile, BK=32, 4 waves x 64x64 (16 MFMA/wave/K-step).
// A fp32 staged raw (cvt at read, VALU overlaps MFMA m114); both-sides
// slot swizzle on source + read (LDS dest linear, rule #21).
template <typename AT, typename CT>
__global__ __launch_bounds__(256) void gemm_dbuf_kernel(
    const AT* __restrict__ A, const __bf16* __restrict__ BT,
    CT* __restrict__ C, int M, int N, int K) {
  __shared__ __align__(16) AT     Asm[2][128 * 32];
  __shared__ __align__(16) __bf16 Bsm[2][128 * 32];
  const int tid = threadIdx.x;
  const int wave = tid >> 6;
  const int lane = tid & 63;
  const int row0 = blockIdx.x * 128;
  const int col0 = blockIdx.y * 128;
  const int wr = (wave >> 1) * 64;
  const int wc = (wave & 1) * 64;
  constexpr int NGLDS = (sizeof(AT) == 4) ? 6 : 4;  // glds issues per wave per stage

  f32x4 acc[4][4] = {};

  // ---- staging helper (issues NGLDS glds16 for this wave) ----
  auto STAGE = [&](int buf, int k0) {
    if constexpr (sizeof(AT) == 4) {
      #pragma unroll
      for (int i = 0; i < 4; ++i) {
        const int rbase = wave * 32 + i * 8;
        int gr = row0 + rbase + (lane >> 3);
        if (gr >= M) gr = M - 1;
        const int ssrc = (lane & 7) ^ (lane >> 3);
        glds16((const float*)A + (size_t)gr * K + k0 + ssrc * 4, &Asm[buf][rbase * 32]);
      }
    } else {
      #pragma unroll
      for (int i = 0; i < 2; ++i) {
        const int rbase = wave * 32 + i * 16;
        int gr = row0 + rbase + (lane >> 2);
        if (gr >= M) gr = M - 1;
        const int ssrc = (lane & 3) ^ ((lane >> 3) & 3);
        glds16((const __bf16*)A + (size_t)gr * K + k0 + ssrc * 8, &Asm[buf][rbase * 32]);
      }
    }
    #pragma unroll
    for (int j = 0; j < 2; ++j) {
      const int rbase = wave * 32 + j * 16;
      const int gr = col0 + rbase + (lane >> 2);
      const int ssrc = (lane & 3) ^ ((lane >> 3) & 3);
      glds16(BT + (size_t)gr * K + k0 + ssrc * 8, &Bsm[buf][rbase * 32]);
    }
  };

  const int NT = K / 32;
  STAGE(0, 0);  // prologue

  for (int t = 0; t < NT; ++t) {
    const int cur = t & 1;
    if (t + 1 < NT) {
      STAGE(cur ^ 1, (t + 1) * 32);
      asm volatile("s_waitcnt vmcnt(%0)" :: "i"(NGLDS) : "memory");
    } else {
      asm volatile("s_waitcnt vmcnt(0)" ::: "memory");
    }
    __builtin_amdgcn_s_barrier();          // cur buffer collectively visible
    __builtin_amdgcn_sched_barrier(0);     // no hoisting of reads above

    const int q = lane >> 4;
    bf16x8 af[4], bfr[4];
    #pragma unroll
    for (int m = 0; m < 4; ++m) {
      const int row = wr + m * 16 + (lane & 15);
      if constexpr (sizeof(AT) == 4) {
        const int sw = row & 7;
        f32x4 lo = *(const f32x4*)&((const float*)&Asm[cur][0])[row * 32 + (((2 * q) ^ sw) * 4)];
        f32x4 hi = *(const f32x4*)&((const float*)&Asm[cur][0])[row * 32 + (((2 * q + 1) ^ sw) * 4)];
        bf16x8 o;
        o[0] = (__bf16)lo[0]; o[1] = (__bf16)lo[1]; o[2] = (__bf16)lo[2]; o[3] = (__bf16)lo[3];
        o[4] = (__bf16)hi[0]; o[5] = (__bf16)hi[1]; o[6] = (__bf16)hi[2]; o[7] = (__bf16)hi[3];
        af[m] = o;
      } else {
        const int sw = (row >> 1) & 3;
        af[m] = *(const bf16x8*)&((const __bf16*)&Asm[cur][0])[row * 32 + ((q ^ sw) * 8)];
      }
    }
    #pragma unroll
    for (int n = 0; n < 4; ++n) {
      const int row = wc + n * 16 + (lane & 15);
      const int sw = (row >> 1) & 3;
      bfr[n] = *(const bf16x8*)&Bsm[cur][row * 32 + ((q ^ sw) * 8)];
    }
    #pragma unroll
    for (int m = 0; m < 4; ++m)
      #pragma unroll
      for (int n = 0; n < 4; ++n)
        acc[m][n] = __builtin_amdgcn_mfma_f32_16x16x32_bf16(af[m], bfr[n], acc[m][n], 0, 0, 0);

    __builtin_amdgcn_sched_barrier(0);
    __builtin_amdgcn_s_barrier();          // cur buffer free for restage
  }

  // Epilogue: D layout col=lane&15, row=(lane>>4)*4+j (m89-verified)
  #pragma unroll
  for (int m = 0; m < 4; ++m) {
    const int r = row0 + wr + m * 16 + (lane >> 4) * 4;
    #pragma unroll
    for (int n = 0; n < 4; ++n) {
      const int c = col0 + wc + n * 16 + (lane & 15);
      #pragma unroll
      for (int j = 0; j < 4; ++j)
        if (r + j < M) C[(size_t)(r + j) * N + c] = (CT)acc[m][n][j];
    }
  }
}

// ---------------------------------------------------------------------------
// Fused GCN aggregate + bias + LayerNorm + ReLU (fp32 xw input).
template <int F, int TPB, typename OutT>
__global__ __launch_bounds__(TPB) void gcn_agg_ln_relu_kernel(
    const float* __restrict__ xw, const float* __restrict__ dinv,
    const int* __restrict__ rowptr, const int* __restrict__ csr_src,
    const float* __restrict__ bias, const float* __restrict__ gamma,
    const float* __restrict__ beta, OutT* __restrict__ h) {
  constexpr int NF = (F + TPB - 1) / TPB;
  const int i = blockIdx.x;
  const int tid = threadIdx.x;
  const float di = dinv[i];
  float acc[NF];
  #pragma unroll
  for (int q = 0; q < NF; ++q) {
    int f = tid + q * TPB;
    acc[q] = (f < F) ? di * xw[(size_t)i * F + f] : 0.f;  // self loop
  }
  const int beg = rowptr[i], end = rowptr[i + 1];
  for (int j = beg; j < end; ++j) {
    int s = csr_src[j];
    float c = dinv[s];
    const float* row = xw + (size_t)s * F;
    #pragma unroll
    for (int q = 0; q < NF; ++q) {
      int f = tid + q * TPB;
      if (f < F) acc[q] += c * row[f];
    }
  }
  float sum = 0.f, sumsq = 0.f;
  #pragma unroll
  for (int q = 0; q < NF; ++q) {
    int f = tid + q * TPB;
    if (f < F) {
      float v = di * acc[q] + bias[f];
      acc[q] = v;
      sum += v;
      sumsq += v * v;
    }
  }
  #pragma unroll
  for (int m = 32; m >= 1; m >>= 1) {
    sum += __shfl_xor(sum, m);
    sumsq += __shfl_xor(sumsq, m);
  }
  constexpr int NW = TPB / 64;
  __shared__ float red[2][NW];
  const int wid = tid >> 6, lane = tid & 63;
  if (lane == 0) { red[0][wid] = sum; red[1][wid] = sumsq; }
  __syncthreads();
  if (tid == 0) {
    float a = 0.f, b2 = 0.f;
    for (int w = 0; w < NW; ++w) { a += red[0][w]; b2 += red[1][w]; }
    red[0][0] = a;
    red[1][0] = b2;
  }
  __syncthreads();
  const float mu = red[0][0] / F;
  const float var = red[1][0] / F - mu * mu;
  const float rstd = rsqrtf(var + LN_EPS);
  #pragma unroll
  for (int q = 0; q < NF; ++q) {
    int f = tid + q * TPB;
    if (f < F) h[(size_t)i * F + f] = (OutT)fmaxf(0.f, (acc[q] - mu) * rstd * gamma[f] + beta[f]);
  }
}

// bf16-input variant: each thread owns 2 consecutive features (one 4B load
// per neighbor row -> coalesced). F == 2*TPB. fp32 accumulate, OutT out.
template <int F, int TPB, typename OutT>
__global__ __launch_bounds__(TPB) void gcn_agg_ln_relu_bf16_kernel(
    const __bf16* __restrict__ xw, const float* __restrict__ dinv,
    const int* __restrict__ rowptr, const int* __restrict__ csr_src,
    const float* __restrict__ bias, const float* __restrict__ gamma,
    const float* __restrict__ beta, OutT* __restrict__ h) {
  static_assert(F == 2 * TPB, "layout");
  const int i = blockIdx.x;
  const int tid = threadIdx.x;
  const int f0 = tid * 2;
  const float di = dinv[i];
  bf16x2 v = *(const bf16x2*)&xw[(size_t)i * F + f0];
  float a0 = di * (float)v[0];
  float a1 = di * (float)v[1];
  const int beg = rowptr[i], end = rowptr[i + 1];
  for (int j = beg; j < end; ++j) {
    int s = csr_src[j];
    float c = dinv[s];
    bf16x2 r = *(const bf16x2*)&xw[(size_t)s * F + f0];
    a0 += c * (float)r[0];
    a1 += c * (float)r[1];
  }
  a0 = di * a0 + bias[f0];
  a1 = di * a1 + bias[f0 + 1];
  float sum = a0 + a1;
  float sumsq = a0 * a0 + a1 * a1;
  #pragma unroll
  for (int m = 32; m >= 1; m >>= 1) {
    sum += __shfl_xor(sum, m);
    sumsq += __shfl_xor(sumsq, m);
  }
  constexpr int NW = TPB / 64;
  __shared__ float red[2][NW];
  const int wid = tid >> 6, lane = tid & 63;
  if (lane == 0) { red[0][wid] = sum; red[1][wid] = sumsq; }
  __syncthreads();
  if (tid == 0) {
    float a = 0.f, b2 = 0.f;
    for (int w = 0; w < NW; ++w) { a += red[0][w]; b2 += red[1][w]; }
    red[0][0] = a;
    red[1][0] = b2;
  }
  __syncthreads();
  const float mu = red[0][0] / F;
  const float var = red[1][0] / F - mu * mu;
  const float rstd = rsqrtf(var + LN_EPS);
  float o0 = fmaxf(0.f, (a0 - mu) * rstd * gamma[f0] + beta[f0]);
  float o1 = fmaxf(0.f, (a1 - mu) * rstd * gamma[f0 + 1] + beta[f0 + 1]);
  if constexpr (sizeof(OutT) == 2) {
    bf16x2 o; o[0] = (__bf16)o0; o[1] = (__bf16)o1;
    *(bf16x2*)&((__bf16*)h)[(size_t)i * F + f0] = o;
  } else {
    float2 o = make_float2(o0, o1);
    *(float2*)&((float*)h)[(size_t)i * F + f0] = o;
  }
}

// ---------------------------------------------------------------------------
// fp32 tiled GEMM (kept for the tiny GEMM3 / GAT-GEMM). 256 threads.
template <int BM, int BN, int BK, int TM, int TN>
__global__ __launch_bounds__((BM / TM) * (BN / TN)) void sgemm_kernel(
    const float* __restrict__ A, const float* __restrict__ B, float* __restrict__ C,
    int M, int N, int K) {
  constexpr int THREADS = (BM / TM) * (BN / TN);
  __shared__ float As[BK][BM + 4];
  __shared__ float Bs[BK][BN];
  const int tid = threadIdx.x;
  const int tcol = tid % (BN / TN);
  const int trow = tid / (BN / TN);
  const int row0 = blockIdx.y * BM;
  const int col0 = blockIdx.x * BN;
  float acc[TM][TN] = {};
  for (int k0 = 0; k0 < K; k0 += BK) {
    constexpr int A4 = BM * BK / 4;
    #pragma unroll
    for (int i = tid; i < A4; i += THREADS) {
      int r = i / (BK / 4);
      int c4 = i % (BK / 4);
      int gr = row0 + r;
      float4 v = make_float4(0.f, 0.f, 0.f, 0.f);
      if (gr < M) v = *(const float4*)(A + (size_t)gr * K + k0 + c4 * 4);
      As[c4 * 4 + 0][r] = v.x;
      As[c4 * 4 + 1][r] = v.y;
      As[c4 * 4 + 2][r] = v.z;
      As[c4 * 4 + 3][r] = v.w;
    }
    constexpr int B4 = BK * BN / 4;
    #pragma unroll
    for (int i = tid; i < B4; i += THREADS) {
      int r = i / (BN / 4);
      int c4 = i % (BN / 4);
      float4 v = *(const float4*)(B + (size_t)(k0 + r) * N + col0 + c4 * 4);
      *(float4*)(&Bs[r][c4 * 4]) = v;
    }
    __syncthreads();
    #pragma unroll
    for (int kk = 0; kk < BK; ++kk) {
      float ra[TM], rb[TN];
      #pragma unroll
      for (int i = 0; i < TM; ++i) ra[i] = As[kk][trow * TM + i];
      #pragma unroll
      for (int j = 0; j < TN; ++j) rb[j] = Bs[kk][tcol * TN + j];
      #pragma unroll
      for (int i = 0; i < TM; ++i)
        #pragma unroll
        for (int j = 0; j < TN; ++j) acc[i][j] = fmaf(ra[i], rb[j], acc[i][j]);
    }
    __syncthreads();
  }
  #pragma unroll
  for (int i = 0; i < TM; ++i) {
    int gr = row0 + trow * TM + i;
    if (gr >= M) continue;
    #pragma unroll
    for (int j = 0; j < TN; ++j) {
      int gc = col0 + tcol * TN + j;
      if (gc < N) C[(size_t)gr * N + gc] = acc[i][j];
    }
  }
}

// ---------------------------------------------------------------------------
// GAT: per-node attention scores s_src, s_dst (dot with att vectors)
__global__ void gat_sdots_kernel(const float* __restrict__ xwg,
                                 const float* __restrict__ att_src,
                                 const float* __restrict__ att_dst,
                                 float* __restrict__ s_src, float* __restrict__ s_dst, int n) {
  int gid = blockIdx.x * blockDim.x + threadIdx.x;
  int node = gid >> 5;
  int l = threadIdx.x & 31;
  if (node >= n) return;
  float v = xwg[(size_t)node * 32 + l];
  float vs = v * att_src[l];
  float vd = v * att_dst[l];
  #pragma unroll
  for (int m = 16; m >= 1; m >>= 1) {
    vs += __shfl_xor(vs, m);
    vd += __shfl_xor(vd, m);
  }
  if (l == 0) { s_src[node] = vs; s_dst[node] = vd; }
}

__device__ __forceinline__ float leaky02(float x) { return x > 0.f ? x : 0.2f * x; }

// GAT online-softmax aggregate + bias + ReLU + pooled partial accumulation.
// 64 threads = 2 softmax groups (lane>>5), alternate edges, shfl-combine.
__global__ __launch_bounds__(64) void gat_agg_kernel(
    const float* __restrict__ xwg, const float* __restrict__ s_src,
    const float* __restrict__ s_dst, const int* __restrict__ rowptr,
    const int* __restrict__ csr_src, const float* __restrict__ bg,
    float* __restrict__ pooled_part) {
  const int i = blockIdx.x;
  const int lane = threadIdx.x;
  const int f = lane & 31;
  const int half = lane >> 5;
  const float sd = s_dst[i];
  // group 0 takes the self loop; group 1 starts empty
  float m, den, acc;
  if (half == 0) {
    m = leaky02(s_src[i] + sd);
    den = 1.f;
    acc = xwg[(size_t)i * 32 + f];
  } else {
    m = -3.0e38f;
    den = 0.f;
    acc = 0.f;
  }
  const int beg = rowptr[i], end = rowptr[i + 1];
  for (int j = beg + half; j < end; j += 2) {
    int s = csr_src[j];
    float a = leaky02(s_src[s] + sd);
    float mn = fmaxf(m, a);
    float sc = __expf(m - mn);
    float ea = __expf(a - mn);
    acc = acc * sc + ea * xwg[(size_t)s * 32 + f];
    den = den * sc + ea;
    m = mn;
  }
  // combine the two groups
  float m_o = __shfl_xor(m, 32);
  float den_o = __shfl_xor(den, 32);
  float acc_o = __shfl_xor(acc, 32);
  float mn = fmaxf(m, m_o);
  float sc = __expf(m - mn);
  float so = __expf(m_o - mn);
  float den_t = den * sc + den_o * so;
  float acc_t = acc * sc + acc_o * so;
  float out = fmaxf(acc_t / den_t + bg[f], 0.f);
  if (lane < 32) atomicAdd(&pooled_part[(size_t)(i & (NPART - 1)) * 32 + f], out);
}

__global__ __launch_bounds__(64) void final_fc_kernel(const float* __restrict__ pooled_part,
                                                      const float* __restrict__ fc_w,
                                                      const float* __restrict__ fc_b,
                                                      float* __restrict__ out, float invN) {
  const int lane = threadIdx.x;
  const int f = lane & 31, half = lane >> 5;
  float p = 0.f;
  #pragma unroll
  for (int b = 0; b < NPART / 2; ++b)
    p += pooled_part[(size_t)(half * (NPART / 2) + b) * 32 + f];
  p += __shfl_xor(p, 32);
  p *= invN;
  #pragma unroll
  for (int c = 0; c < 2; ++c) {
    float v = (lane < 32) ? p * fc_w[f * 2 + c] : 0.f;
    #pragma unroll
    for (int m = 16; m >= 1; m >>= 1) v += __shfl_xor(v, m);
    if (lane == 0) out[c] = v + fc_b[c];
  }
}

// ---------------------------------------------------------------------------
extern "C" void kernel_launch(void* const* d_in, const int* in_sizes, int n_in,
                              void* d_out, int out_size, void* d_ws, size_t ws_size,
                              hipStream_t stream) {
  const float* x       = (const float*)d_in[0];
  const void*  edges   = d_in[1];
  const float* W1      = (const float*)d_in[2];
  const float* b1      = (const float*)d_in[3];
  const float* ln1_g   = (const float*)d_in[4];
  const float* ln1_b   = (const float*)d_in[5];
  const float* W2      = (const float*)d_in[6];
  const float* b2      = (const float*)d_in[7];
  const float* ln2_g   = (const float*)d_in[8];
  const float* ln2_b   = (const float*)d_in[9];
  const float* W3      = (const float*)d_in[10];
  const float* b3      = (const float*)d_in[11];
  const float* ln3_g   = (const float*)d_in[12];
  const float* ln3_b   = (const float*)d_in[13];
  const float* Wg      = (const float*)d_in[14];
  const float* att_src = (const float*)d_in[15];
  const float* att_dst = (const float*)d_in[16];
  const float* bg      = (const float*)d_in[17];
  const float* fc_w    = (const float*)d_in[18];
  const float* fc_b    = (const float*)d_in[19];
  float* out = (float*)d_out;

  const int N = N_NODES, E = N_EDGES;

  // workspace layout
  char* ws = (char*)d_ws;
  size_t off = 0;
  auto alloc = [&](size_t bytes) {
    size_t o = off;
    off = (off + bytes + 255) & ~(size_t)255;
    return o;
  };
  size_t o_bufA   = alloc((size_t)N * DIM_H1 * 4);
  size_t o_bufB   = alloc((size_t)N * DIM_H1 * 4);
  size_t o_w1t    = alloc((size_t)DIM_IN * DIM_H1 * 2);
  size_t o_w2t    = alloc((size_t)DIM_H1 * DIM_H2 * 2);
  size_t o_src    = alloc((size_t)E * 4);
  size_t o_dst    = alloc((size_t)E * 4);
  size_t o_csr    = alloc((size_t)E * 4);
  size_t o_cnt    = alloc((size_t)N * 4);
  size_t o_rowptr = alloc((size_t)(N + 1) * 4);
  size_t o_cursor = alloc((size_t)N * 4);
  size_t o_dinv   = alloc((size_t)N * 4);
  size_t o_ssrc   = alloc((size_t)N * 4);
  size_t o_sdst   = alloc((size_t)N * 4);
  size_t o_pooled = alloc((size_t)NPART * 32 * 4);
  size_t o_flag   = alloc(4);

  float* bufA   = (float*)(ws + o_bufA);
  float* bufB   = (float*)(ws + o_bufB);
  __bf16* W1T   = (__bf16*)(ws + o_w1t);
  __bf16* W2T   = (__bf16*)(ws + o_w2t);
  int*   srcI   = (int*)(ws + o_src);
  int*   dstI   = (int*)(ws + o_dst);
  int*   csr    = (int*)(ws + o_csr);
  int*   cnt    = (int*)(ws + o_cnt);
  int*   rowptr = (int*)(ws + o_rowptr);
  int*   cursor = (int*)(ws + o_cursor);
  float* dinv   = (float*)(ws + o_dinv);
  float* ssrc   = (float*)(ws + o_ssrc);
  float* sdst   = (float*)(ws + o_sdst);
  float* pooled = (float*)(ws + o_pooled);
  int*   flag   = (int*)(ws + o_flag);

  hipMemsetAsync(cnt, 0, (size_t)N * 4, stream);
  hipMemsetAsync(pooled, 0, (size_t)NPART * 32 * 4, stream);

  const int EB = (E + 255) / 256;

  // Graph preprocessing (CSR by dst, reused by all 4 conv layers)
  detect_fmt_kernel<<<1, 1, 0, stream>>>(edges, flag);
  convert_edges_kernel<<<EB, 256, 0, stream>>>(edges, flag, srcI, dstI, cnt, E);
  scan_kernel<<<1, 1024, 0, stream>>>(cnt, rowptr, cursor, N);
  scatter_kernel<<<EB, 256, 0, stream>>>(srcI, dstI, cursor, csr, E);
  dinv_kernel<<<(N + 255) / 256, 256, 0, stream>>>(cnt, dinv, N);

  // Weight transposes (bf16 B^T operands for the MFMA GEMMs)
  transpose_cvt_kernel<<<dim3(DIM_IN / 32, DIM_H1 / 32), 256, 0, stream>>>(W1, W1T, DIM_IN, DIM_H1);
  transpose_cvt_kernel<<<dim3(DIM_H1 / 32, DIM_H2 / 32), 256, 0, stream>>>(W2, W2T, DIM_H1, DIM_H2);

  const int MB128 = (N + 127) / 128;  // 157

  // Layer 1: xw1 = x @ W1 (dbuf MFMA, counted vmcnt, bf16 out)
  gemm_dbuf_kernel<float, __bf16>
      <<<dim3(MB128, DIM_H1 / 128), 256, 0, stream>>>(x, W1T, (__bf16*)bufA, N, DIM_H1, DIM_IN);
  gcn_agg_ln_relu_bf16_kernel<DIM_H1, 256, __bf16>
      <<<N, 256, 0, stream>>>((const __bf16*)bufA, dinv, rowptr, csr, b1, ln1_g, ln1_b, (__bf16*)bufB);

  // Layer 2: xw2 = h1(bf16) @ W2 (bf16 out)
  gemm_dbuf_kernel<__bf16, __bf16>
      <<<dim3(MB128, DIM_H2 / 128), 256, 0, stream>>>((const __bf16*)bufB, W2T, (__bf16*)bufA, N, DIM_H2, DIM_H1);
  gcn_agg_ln_relu_bf16_kernel<DIM_H2, 64, float>
      <<<N, 64, 0, stream>>>((const __bf16*)bufA, dinv, rowptr, csr, b2, ln2_g, ln2_b, bufB);

  // Layer 3: xw3 = h2 @ W3 (20000x128x32, tiny -> fp32 sgemm)
  sgemm_kernel<128, 32, 16, 8, 2>
      <<<dim3(1, MB128), 256, 0, stream>>>(bufB, W3, bufA, N, DIM_H3, DIM_H2);
  gcn_agg_ln_relu_kernel<DIM_H3, 64, float>
      <<<N, 64, 0, stream>>>(bufA, dinv, rowptr, csr, b3, ln3_g, ln3_b, bufB);

  // GAT: xwg = h3 @ Wg (20000x32x32)
  sgemm_kernel<128, 32, 16, 8, 2>
      <<<dim3(1, MB128), 256, 0, stream>>>(bufB, Wg, bufA, N, DIM_H3, DIM_H3);
  gat_sdots_kernel<<<(N * 32 + 255) / 256, 256, 0, stream>>>(bufA, att_src, att_dst, ssrc, sdst, N);
  gat_agg_kernel<<<N, 64, 0, stream>>>(bufA, ssrc, sdst, rowptr, csr, bg, pooled);

  final_fc_kernel<<<1, 64, 0, stream>>>(pooled, fc_w, fc_b, out, 1.f / (float)N);
}